// Round 1
// baseline (720.165 us; speedup 1.0000x reference)
//
#include <hip/hip_runtime.h>
#include <math.h>

#define C_DIM 128

static inline int ceil_div(int a, int b) { return (a + b - 1) / b; }

// ---------------- degree count (in-degree over col) ----------------
__global__ void k_count(const int* __restrict__ col, int E, int* __restrict__ deg) {
    int i = blockIdx.x * blockDim.x + threadIdx.x;
    if (i < E) atomicAdd(&deg[col[i]], 1);
}

// ---------------- scan stage 1: per-1024-block exclusive scan ----------------
__global__ void k_scan1(const int* __restrict__ deg, int n,
                        int* __restrict__ offs, int* __restrict__ bsum) {
    __shared__ int sd[256];
    int t = threadIdx.x;
    int base = blockIdx.x * 1024;
    int v[4]; int s = 0;
#pragma unroll
    for (int i = 0; i < 4; ++i) {
        int idx = base + t * 4 + i;
        v[i] = (idx < n) ? deg[idx] : 0;
        s += v[i];
    }
    sd[t] = s;
    __syncthreads();
    for (int off = 1; off < 256; off <<= 1) {
        int x = (t >= off) ? sd[t - off] : 0;
        __syncthreads();
        sd[t] += x;
        __syncthreads();
    }
    if (t == 255) bsum[blockIdx.x] = sd[255];
    int run = sd[t] - s;  // exclusive prefix for this thread
#pragma unroll
    for (int i = 0; i < 4; ++i) {
        int idx = base + t * 4 + i;
        if (idx < n) offs[idx] = run;
        run += v[i];
    }
}

// ---------------- scan stage 2: scan the block sums (nb <= 128) ----------------
__global__ void k_scan2(int* __restrict__ bsum, int nb, int* __restrict__ offs_total) {
    __shared__ int sd[128];
    int t = threadIdx.x;
    int v = (t < nb) ? bsum[t] : 0;
    sd[t] = v;
    __syncthreads();
    for (int off = 1; off < 128; off <<= 1) {
        int x = (t >= off) ? sd[t - off] : 0;
        __syncthreads();
        sd[t] += x;
        __syncthreads();
    }
    if (t < nb) bsum[t] = sd[t] - v;  // exclusive
    if (t == 127) offs_total[0] = sd[127];
}

// ---------------- scan stage 3: add block offsets, copy to cursor ----------------
__global__ void k_scan3(int* __restrict__ offs, const int* __restrict__ bsum,
                        int* __restrict__ cursor, int n) {
    int i = blockIdx.x * blockDim.x + threadIdx.x;
    if (i < n) {
        int v = offs[i] + bsum[i >> 10];
        offs[i] = v;
        cursor[i] = v;
    }
}

// ---------------- CSR fill: csr[slot] = source row, bucketed by col ----------------
__global__ void k_fill(const int* __restrict__ row, const int* __restrict__ col, int E,
                       int* __restrict__ cursor, int* __restrict__ csr) {
    int i = blockIdx.x * blockDim.x + threadIdx.x;
    if (i < E) {
        int c = col[i];
        int slot = atomicAdd(&cursor[c], 1);
        csr[slot] = row[i];
    }
}

// ---------------- dinv = (deg+1)^-0.5  (deg counts in-edges; +1 = self loop) ----
__global__ void k_dinv(const int* __restrict__ deg, float* __restrict__ dinv, int n) {
    int i = blockIdx.x * blockDim.x + threadIdx.x;
    if (i < n) dinv[i] = 1.0f / sqrtf((float)deg[i] + 1.0f);
}

// ---------------- matmul [N,128]@[128,128], epilogue scale by dinv[row] -------
// Block: 256 threads, 32 rows x 128 cols; thread = 4 rows x 4 cols.
// LDS: A tile padded to stride 132 (bank-conflict-free), W half-tiles of 64 rows.
__global__ __launch_bounds__(256) void k_matmul_scale(
    const float* __restrict__ A, const float* __restrict__ W,
    const float* __restrict__ dinv, float* __restrict__ C, int N) {
    __shared__ float As[32 * 132];   // 16.9 KB
    __shared__ float Ws[64 * 128];   // 32 KB
    int t = threadIdx.x;
    int row0 = blockIdx.x * 32;
    int rows = N - row0; if (rows > 32) rows = 32;

    {   // stage A tile (float4 global reads, padded LDS writes)
        const float4* Ag = (const float4*)(A + (size_t)row0 * C_DIM);
        for (int i = t; i < rows * 32; i += 256) {
            int r = i >> 5, kq = i & 31;
            float4 v = Ag[i];
            *(float4*)&As[r * 132 + kq * 4] = v;
        }
    }

    int cg = (t & 31) * 4;       // col base 0..124
    int rg = (t >> 5) * 4;       // row base 0..28
    float acc[4][4] = {};

    for (int kh = 0; kh < 2; ++kh) {
        __syncthreads();
        {   // stage W half: rows [kh*64, kh*64+64)
            const float4* Wg = (const float4*)(W + (size_t)kh * 64 * C_DIM);
            float4* Wsv = (float4*)Ws;
            for (int i = t; i < 64 * 32; i += 256) Wsv[i] = Wg[i];
        }
        __syncthreads();
        for (int k = 0; k < 64; k += 4) {
            float4 a[4];
#pragma unroll
            for (int i = 0; i < 4; ++i)
                a[i] = *(const float4*)&As[(rg + i) * 132 + kh * 64 + k];
#pragma unroll
            for (int kk = 0; kk < 4; ++kk) {
                float4 w = *(const float4*)&Ws[(k + kk) * C_DIM + cg];
#pragma unroll
                for (int i = 0; i < 4; ++i) {
                    float av = (kk == 0) ? a[i].x : (kk == 1) ? a[i].y
                             : (kk == 2) ? a[i].z : a[i].w;
                    acc[i][0] += av * w.x;
                    acc[i][1] += av * w.y;
                    acc[i][2] += av * w.z;
                    acc[i][3] += av * w.w;
                }
            }
        }
    }

#pragma unroll
    for (int i = 0; i < 4; ++i) {
        if (rg + i < rows) {
            int r = row0 + rg + i;
            float s = dinv[r];
            float4 o;
            o.x = acc[i][0] * s; o.y = acc[i][1] * s;
            o.z = acc[i][2] * s; o.w = acc[i][3] * s;
            *(float4*)&C[(size_t)r * C_DIM + cg] = o;
        }
    }
}

// ---------------- per-node gather-reduce aggregation ----------------
// One wave (64 lanes) per node, float2 per lane. out = act(dinv[n]*(sum+self)+b)
__global__ __launch_bounds__(64) void k_aggregate(
    const float* __restrict__ hs, const int* __restrict__ offs,
    const int* __restrict__ csr, const float* __restrict__ dinv,
    const float* __restrict__ bias, float* __restrict__ out, int do_relu) {
    int node = blockIdx.x;
    int t = threadIdx.x;  // 0..63
    int s = offs[node], e = offs[node + 1];
    float2 acc = ((const float2*)(hs + (size_t)node * C_DIM))[t];  // self-loop
    int j = s;
    for (; j + 4 <= e; j += 4) {
        int r0 = csr[j + 0], r1 = csr[j + 1], r2 = csr[j + 2], r3 = csr[j + 3];
        float2 v0 = ((const float2*)(hs + (size_t)r0 * C_DIM))[t];
        float2 v1 = ((const float2*)(hs + (size_t)r1 * C_DIM))[t];
        float2 v2 = ((const float2*)(hs + (size_t)r2 * C_DIM))[t];
        float2 v3 = ((const float2*)(hs + (size_t)r3 * C_DIM))[t];
        acc.x += v0.x + v1.x + v2.x + v3.x;
        acc.y += v0.y + v1.y + v2.y + v3.y;
    }
    for (; j < e; ++j) {
        int r = csr[j];
        float2 v = ((const float2*)(hs + (size_t)r * C_DIM))[t];
        acc.x += v.x; acc.y += v.y;
    }
    float dn = dinv[node];
    float ox = dn * acc.x + bias[2 * t];
    float oy = dn * acc.y + bias[2 * t + 1];
    if (do_relu) { ox = fmaxf(ox, 0.f); oy = fmaxf(oy, 0.f); }
    ((float2*)(out + (size_t)node * C_DIM))[t] = make_float2(ox, oy);
}

// ---------------- fused scatter-mean pool + MLP (128->64->1) ----------------
__global__ __launch_bounds__(128) void k_pool_mlp(
    const float* __restrict__ h, const int* __restrict__ batch, int n,
    const float* __restrict__ Wm1, const float* __restrict__ bm1,
    const float* __restrict__ Wm2, const float* __restrict__ bm2,
    float* __restrict__ out) {
    int g = blockIdx.x;
    int t = threadIdx.x;  // 128 threads, one column each
    // binary search [start,end) in sorted batch
    int lo = 0, hi = n;
    while (lo < hi) { int m = (lo + hi) >> 1; if (batch[m] < g) lo = m + 1; else hi = m; }
    int start = lo;
    lo = start; hi = n;
    while (lo < hi) { int m = (lo + hi) >> 1; if (batch[m] < g + 1) lo = m + 1; else hi = m; }
    int end = lo;

    float s = 0.f;
    for (int i = start; i < end; ++i) s += h[(size_t)i * C_DIM + t];
    float cnt = (float)(end - start);
    float mean = s / fmaxf(cnt, 1.0f);

    __shared__ float m_s[128];
    __shared__ float hid[64];
    m_s[t] = mean;
    __syncthreads();
    if (t < 64) {
        float a = bm1[t];
#pragma unroll 4
        for (int k = 0; k < 128; ++k) a += m_s[k] * Wm1[k * 64 + t];
        hid[t] = fmaxf(a, 0.f) * Wm2[t];
    }
    __syncthreads();
    if (t < 64) {
        float v = hid[t];
        for (int off = 32; off > 0; off >>= 1) v += __shfl_down(v, off);
        if (t == 0) out[g] = v + bm2[0];
    }
}

extern "C" void kernel_launch(void* const* d_in, const int* in_sizes, int n_in,
                              void* d_out, int out_size, void* d_ws, size_t ws_size,
                              hipStream_t stream) {
    const float* x     = (const float*)d_in[0];
    const int*   eidx  = (const int*)d_in[1];
    const int*   batch = (const int*)d_in[2];
    const float* W1    = (const float*)d_in[3];
    const float* b1    = (const float*)d_in[4];
    const float* W2    = (const float*)d_in[5];
    const float* b2    = (const float*)d_in[6];
    const float* Wm1   = (const float*)d_in[7];
    const float* bm1   = (const float*)d_in[8];
    const float* Wm2   = (const float*)d_in[9];
    const float* bm2   = (const float*)d_in[10];

    const int N = in_sizes[2];       // 100000
    const int E = in_sizes[1] / 2;   // 1600000
    const int G = out_size;          // 512

    char* p = (char*)d_ws;
    auto carve = [&](size_t bytes) {
        char* q = p;
        p += (bytes + 255) & ~(size_t)255;
        return q;
    };
    float* bufA   = (float*)carve((size_t)N * C_DIM * sizeof(float));
    float* bufB   = (float*)carve((size_t)N * C_DIM * sizeof(float));
    float* dinv   = (float*)carve((size_t)N * sizeof(float));
    int*   deg    = (int*)  carve((size_t)N * sizeof(int));
    int*   offs   = (int*)  carve((size_t)(N + 1) * sizeof(int));
    int*   cursor = (int*)  carve((size_t)N * sizeof(int));
    int*   csr    = (int*)  carve((size_t)E * sizeof(int));
    int*   bsum   = (int*)  carve(128 * sizeof(int));

    const int* erow = eidx;
    const int* ecol = eidx + E;

    // --- CSR-by-destination build (once per call) ---
    hipMemsetAsync(deg, 0, (size_t)N * sizeof(int), stream);
    k_count<<<ceil_div(E, 256), 256, 0, stream>>>(ecol, E, deg);
    int nb = ceil_div(N, 1024);
    k_scan1<<<nb, 256, 0, stream>>>(deg, N, offs, bsum);
    k_scan2<<<1, 128, 0, stream>>>(bsum, nb, offs + N);
    k_scan3<<<ceil_div(N, 256), 256, 0, stream>>>(offs, bsum, cursor, N);
    k_fill<<<ceil_div(E, 256), 256, 0, stream>>>(erow, ecol, E, cursor, csr);
    k_dinv<<<ceil_div(N, 256), 256, 0, stream>>>(deg, dinv, N);

    // --- conv1: bufA = dinv ⊙ (x@W1); bufB = relu(dinv*(agg+self)+b1) ---
    k_matmul_scale<<<ceil_div(N, 32), 256, 0, stream>>>(x, W1, dinv, bufA, N);
    k_aggregate<<<N, 64, 0, stream>>>(bufA, offs, csr, dinv, b1, bufB, 1);
    // --- conv2 ---
    k_matmul_scale<<<ceil_div(N, 32), 256, 0, stream>>>(bufB, W2, dinv, bufA, N);
    k_aggregate<<<N, 64, 0, stream>>>(bufA, offs, csr, dinv, b2, bufB, 0);
    // --- pool + MLP ---
    k_pool_mlp<<<G, 128, 0, stream>>>(bufB, batch, N, Wm1, bm1, Wm2, bm2, (float*)d_out);
}

// Round 2
// 664.203 us; speedup vs baseline: 1.0843x; 1.0843x over previous
//
#include <hip/hip_runtime.h>
#include <math.h>

#define C_DIM 128

static inline int ceil_div(int a, int b) { return (a + b - 1) / b; }

// ---------------- XCD-partitioned degree count (in-degree over col) ----------
// part = blockIdx % 8 (round-robin XCD heuristic). Each part only counts
// destinations in its contiguous node range -> deg lines stay in one L2.
__global__ __launch_bounds__(256) void k_count_part(
    const int* __restrict__ col, int E, int chunk, float partScale,
    int* __restrict__ deg) {
    int part = blockIdx.x & 7;
    int cb = blockIdx.x >> 3;
    int s = cb * chunk;
    int e = s + chunk; if (e > E) e = E;
    for (int i = s + threadIdx.x; i < e; i += 256) {
        int c = col[i];
        int p = (int)((float)c * partScale);
        p = p > 7 ? 7 : p;
        if (p == part) atomicAdd(&deg[c], 1);
    }
}

// ---------------- scan stage 1: per-1024-block exclusive scan ----------------
__global__ void k_scan1(const int* __restrict__ deg, int n,
                        int* __restrict__ offs, int* __restrict__ bsum) {
    __shared__ int sd[256];
    int t = threadIdx.x;
    int base = blockIdx.x * 1024;
    int v[4]; int s = 0;
#pragma unroll
    for (int i = 0; i < 4; ++i) {
        int idx = base + t * 4 + i;
        v[i] = (idx < n) ? deg[idx] : 0;
        s += v[i];
    }
    sd[t] = s;
    __syncthreads();
    for (int off = 1; off < 256; off <<= 1) {
        int x = (t >= off) ? sd[t - off] : 0;
        __syncthreads();
        sd[t] += x;
        __syncthreads();
    }
    if (t == 255) bsum[blockIdx.x] = sd[255];
    int run = sd[t] - s;  // exclusive prefix for this thread
#pragma unroll
    for (int i = 0; i < 4; ++i) {
        int idx = base + t * 4 + i;
        if (idx < n) offs[idx] = run;
        run += v[i];
    }
}

// ---------------- scan stage 2: scan the block sums (nb <= 128) ----------------
__global__ void k_scan2(int* __restrict__ bsum, int nb, int* __restrict__ offs_total) {
    __shared__ int sd[128];
    int t = threadIdx.x;
    int v = (t < nb) ? bsum[t] : 0;
    sd[t] = v;
    __syncthreads();
    for (int off = 1; off < 128; off <<= 1) {
        int x = (t >= off) ? sd[t - off] : 0;
        __syncthreads();
        sd[t] += x;
        __syncthreads();
    }
    if (t < nb) bsum[t] = sd[t] - v;  // exclusive
    if (t == 127) offs_total[0] = sd[127];
}

// ---------------- scan stage 3: add block offsets, copy to cursor ----------------
__global__ void k_scan3(int* __restrict__ offs, const int* __restrict__ bsum,
                        int* __restrict__ cursor, int n) {
    int i = blockIdx.x * blockDim.x + threadIdx.x;
    if (i < n) {
        int v = offs[i] + bsum[i >> 10];
        offs[i] = v;
        cursor[i] = v;
    }
}

// ---------------- XCD-partitioned CSR fill ----------------
// Same partition function as k_count_part: part's csr slot range is contiguous
// (partition fn monotone in c), so scattered stores stay in one XCD's L2.
__global__ __launch_bounds__(256) void k_fill_part(
    const int* __restrict__ row, const int* __restrict__ col, int E,
    int chunk, float partScale,
    int* __restrict__ cursor, int* __restrict__ csr) {
    int part = blockIdx.x & 7;
    int cb = blockIdx.x >> 3;
    int s = cb * chunk;
    int e = s + chunk; if (e > E) e = E;
    for (int i = s + threadIdx.x; i < e; i += 256) {
        int c = col[i];
        int p = (int)((float)c * partScale);
        p = p > 7 ? 7 : p;
        if (p == part) {
            int slot = atomicAdd(&cursor[c], 1);
            csr[slot] = row[i];
        }
    }
}

// ---------------- dinv = (deg+1)^-0.5  (deg counts in-edges; +1 = self loop) ----
__global__ void k_dinv(const int* __restrict__ deg, float* __restrict__ dinv, int n) {
    int i = blockIdx.x * blockDim.x + threadIdx.x;
    if (i < n) dinv[i] = 1.0f / sqrtf((float)deg[i] + 1.0f);
}

// ---------------- matmul [N,128]@[128,128], epilogue scale by dinv[row] -------
// Block: 256 threads, 32 rows x 128 cols; thread = 4 rows x 4 cols.
__global__ __launch_bounds__(256) void k_matmul_scale(
    const float* __restrict__ A, const float* __restrict__ W,
    const float* __restrict__ dinv, float* __restrict__ C, int N) {
    __shared__ float As[32 * 132];   // 16.9 KB
    __shared__ float Ws[64 * 128];   // 32 KB
    int t = threadIdx.x;
    int row0 = blockIdx.x * 32;
    int rows = N - row0; if (rows > 32) rows = 32;

    {   // stage A tile (float4 global reads, padded LDS writes)
        const float4* Ag = (const float4*)(A + (size_t)row0 * C_DIM);
        for (int i = t; i < rows * 32; i += 256) {
            int r = i >> 5, kq = i & 31;
            float4 v = Ag[i];
            *(float4*)&As[r * 132 + kq * 4] = v;
        }
    }

    int cg = (t & 31) * 4;       // col base 0..124
    int rg = (t >> 5) * 4;       // row base 0..28
    float acc[4][4] = {};

    for (int kh = 0; kh < 2; ++kh) {
        __syncthreads();
        {   // stage W half: rows [kh*64, kh*64+64)
            const float4* Wg = (const float4*)(W + (size_t)kh * 64 * C_DIM);
            float4* Wsv = (float4*)Ws;
            for (int i = t; i < 64 * 32; i += 256) Wsv[i] = Wg[i];
        }
        __syncthreads();
        for (int k = 0; k < 64; k += 4) {
            float4 a[4];
#pragma unroll
            for (int i = 0; i < 4; ++i)
                a[i] = *(const float4*)&As[(rg + i) * 132 + kh * 64 + k];
#pragma unroll
            for (int kk = 0; kk < 4; ++kk) {
                float4 w = *(const float4*)&Ws[(k + kk) * C_DIM + cg];
#pragma unroll
                for (int i = 0; i < 4; ++i) {
                    float av = (kk == 0) ? a[i].x : (kk == 1) ? a[i].y
                             : (kk == 2) ? a[i].z : a[i].w;
                    acc[i][0] += av * w.x;
                    acc[i][1] += av * w.y;
                    acc[i][2] += av * w.z;
                    acc[i][3] += av * w.w;
                }
            }
        }
    }

#pragma unroll
    for (int i = 0; i < 4; ++i) {
        if (rg + i < rows) {
            int r = row0 + rg + i;
            float s = dinv[r];
            float4 o;
            o.x = acc[i][0] * s; o.y = acc[i][1] * s;
            o.z = acc[i][2] * s; o.w = acc[i][3] * s;
            *(float4*)&C[(size_t)r * C_DIM + cg] = o;
        }
    }
}

// ---------------- per-node gather-reduce aggregation ----------------
// 256-thread blocks = 4 waves, one node per wave, float2/lane, unroll-8
// so 8 index loads + 8 row gathers are in flight per lane.
__global__ __launch_bounds__(256) void k_aggregate(
    const float* __restrict__ hs, const int* __restrict__ offs,
    const int* __restrict__ csr, const float* __restrict__ dinv,
    const float* __restrict__ bias, float* __restrict__ out, int do_relu, int N) {
    int node = (blockIdx.x << 2) + (threadIdx.x >> 6);
    if (node >= N) return;
    int t = threadIdx.x & 63;  // lane within wave
    int s = offs[node], e = offs[node + 1];
    float2 acc = ((const float2*)(hs + (size_t)node * C_DIM))[t];  // self-loop
    int j = s;
    for (; j + 8 <= e; j += 8) {
        int r[8];
#pragma unroll
        for (int k = 0; k < 8; ++k) r[k] = csr[j + k];
        float2 v[8];
#pragma unroll
        for (int k = 0; k < 8; ++k)
            v[k] = ((const float2*)(hs + (size_t)r[k] * C_DIM))[t];
#pragma unroll
        for (int k = 0; k < 8; ++k) { acc.x += v[k].x; acc.y += v[k].y; }
    }
    for (; j + 2 <= e; j += 2) {
        int r0 = csr[j], r1 = csr[j + 1];
        float2 v0 = ((const float2*)(hs + (size_t)r0 * C_DIM))[t];
        float2 v1 = ((const float2*)(hs + (size_t)r1 * C_DIM))[t];
        acc.x += v0.x + v1.x; acc.y += v0.y + v1.y;
    }
    if (j < e) {
        int r = csr[j];
        float2 v = ((const float2*)(hs + (size_t)r * C_DIM))[t];
        acc.x += v.x; acc.y += v.y;
    }
    float dn = dinv[node];
    float ox = dn * acc.x + bias[2 * t];
    float oy = dn * acc.y + bias[2 * t + 1];
    if (do_relu) { ox = fmaxf(ox, 0.f); oy = fmaxf(oy, 0.f); }
    ((float2*)(out + (size_t)node * C_DIM))[t] = make_float2(ox, oy);
}

// ---------------- fused scatter-mean pool + MLP (128->64->1) ----------------
__global__ __launch_bounds__(128) void k_pool_mlp(
    const float* __restrict__ h, const int* __restrict__ batch, int n,
    const float* __restrict__ Wm1, const float* __restrict__ bm1,
    const float* __restrict__ Wm2, const float* __restrict__ bm2,
    float* __restrict__ out) {
    int g = blockIdx.x;
    int t = threadIdx.x;  // 128 threads, one column each
    int lo = 0, hi = n;
    while (lo < hi) { int m = (lo + hi) >> 1; if (batch[m] < g) lo = m + 1; else hi = m; }
    int start = lo;
    lo = start; hi = n;
    while (lo < hi) { int m = (lo + hi) >> 1; if (batch[m] < g + 1) lo = m + 1; else hi = m; }
    int end = lo;

    float s = 0.f;
    for (int i = start; i < end; ++i) s += h[(size_t)i * C_DIM + t];
    float cnt = (float)(end - start);
    float mean = s / fmaxf(cnt, 1.0f);

    __shared__ float m_s[128];
    __shared__ float hid[64];
    m_s[t] = mean;
    __syncthreads();
    if (t < 64) {
        float a = bm1[t];
#pragma unroll 4
        for (int k = 0; k < 128; ++k) a += m_s[k] * Wm1[k * 64 + t];
        hid[t] = fmaxf(a, 0.f) * Wm2[t];
    }
    __syncthreads();
    if (t < 64) {
        float v = hid[t];
        for (int off = 32; off > 0; off >>= 1) v += __shfl_down(v, off);
        if (t == 0) out[g] = v + bm2[0];
    }
}

extern "C" void kernel_launch(void* const* d_in, const int* in_sizes, int n_in,
                              void* d_out, int out_size, void* d_ws, size_t ws_size,
                              hipStream_t stream) {
    const float* x     = (const float*)d_in[0];
    const int*   eidx  = (const int*)d_in[1];
    const int*   batch = (const int*)d_in[2];
    const float* W1    = (const float*)d_in[3];
    const float* b1    = (const float*)d_in[4];
    const float* W2    = (const float*)d_in[5];
    const float* b2    = (const float*)d_in[6];
    const float* Wm1   = (const float*)d_in[7];
    const float* bm1   = (const float*)d_in[8];
    const float* Wm2   = (const float*)d_in[9];
    const float* bm2   = (const float*)d_in[10];

    const int N = in_sizes[2];       // 100000
    const int E = in_sizes[1] / 2;   // 1600000
    const int G = out_size;          // 512

    char* p = (char*)d_ws;
    auto carve = [&](size_t bytes) {
        char* q = p;
        p += (bytes + 255) & ~(size_t)255;
        return q;
    };
    float* bufA   = (float*)carve((size_t)N * C_DIM * sizeof(float));
    float* bufB   = (float*)carve((size_t)N * C_DIM * sizeof(float));
    float* dinv   = (float*)carve((size_t)N * sizeof(float));
    int*   deg    = (int*)  carve((size_t)N * sizeof(int));
    int*   offs   = (int*)  carve((size_t)(N + 1) * sizeof(int));
    int*   cursor = (int*)  carve((size_t)N * sizeof(int));
    int*   csr    = (int*)  carve((size_t)E * sizeof(int));
    int*   bsum   = (int*)  carve(128 * sizeof(int));

    const int* erow = eidx;
    const int* ecol = eidx + E;

    const float partScale = 8.0f / (float)N;
    const int nBlkPerPart = 256;
    const int chunk = ceil_div(E, nBlkPerPart);

    // --- CSR-by-destination build (once per call) ---
    hipMemsetAsync(deg, 0, (size_t)N * sizeof(int), stream);
    k_count_part<<<8 * nBlkPerPart, 256, 0, stream>>>(ecol, E, chunk, partScale, deg);
    int nb = ceil_div(N, 1024);
    k_scan1<<<nb, 256, 0, stream>>>(deg, N, offs, bsum);
    k_scan2<<<1, 128, 0, stream>>>(bsum, nb, offs + N);
    k_scan3<<<ceil_div(N, 256), 256, 0, stream>>>(offs, bsum, cursor, N);
    k_fill_part<<<8 * nBlkPerPart, 256, 0, stream>>>(erow, ecol, E, chunk, partScale,
                                                     cursor, csr);
    k_dinv<<<ceil_div(N, 256), 256, 0, stream>>>(deg, dinv, N);

    // --- conv1: bufA = dinv ⊙ (x@W1); bufB = relu(dinv*(agg+self)+b1) ---
    k_matmul_scale<<<ceil_div(N, 32), 256, 0, stream>>>(x, W1, dinv, bufA, N);
    k_aggregate<<<ceil_div(N, 4), 256, 0, stream>>>(bufA, offs, csr, dinv, b1, bufB, 1, N);
    // --- conv2 ---
    k_matmul_scale<<<ceil_div(N, 32), 256, 0, stream>>>(bufB, W2, dinv, bufA, N);
    k_aggregate<<<ceil_div(N, 4), 256, 0, stream>>>(bufA, offs, csr, dinv, b2, bufB, 0, N);
    // --- pool + MLP ---
    k_pool_mlp<<<G, 128, 0, stream>>>(bufB, batch, N, Wm1, bm1, Wm2, bm2, (float*)d_out);
}

// Round 3
// 564.875 us; speedup vs baseline: 1.2749x; 1.1758x over previous
//
#include <hip/hip_runtime.h>
#include <math.h>

#define C_DIM 128
typedef unsigned short ushort_t;

static inline int ceil_div(int a, int b) { return (a + b - 1) / b; }

// bf16 round-to-nearest-even (unbiased — truncation would bias sums by deg*2^-9)
__device__ inline ushort_t f2bf(float f) {
    union { float f; unsigned u; } v; v.f = f;
    unsigned r = v.u + 0x7FFFu + ((v.u >> 16) & 1u);
    return (ushort_t)(r >> 16);
}
__device__ inline float bf2f(unsigned s) {
    union { unsigned u; float f; } v; v.u = s << 16; return v.f;
}

// ---------------- XCD-partitioned degree count (in-degree over col) ----------
__global__ __launch_bounds__(256) void k_count_part(
    const int* __restrict__ col, int E, int chunk, float partScale,
    int* __restrict__ deg) {
    int part = blockIdx.x & 7;
    int cb = blockIdx.x >> 3;
    int s = cb * chunk;
    int e = s + chunk; if (e > E) e = E;
    for (int i = s + threadIdx.x; i < e; i += 256) {
        int c = col[i];
        int p = (int)((float)c * partScale);
        p = p > 7 ? 7 : p;
        if (p == part) atomicAdd(&deg[c], 1);
    }
}

// ---------------- scan stage 1: per-1024-block exclusive scan ----------------
__global__ void k_scan1(const int* __restrict__ deg, int n,
                        int* __restrict__ offs, int* __restrict__ bsum) {
    __shared__ int sd[256];
    int t = threadIdx.x;
    int base = blockIdx.x * 1024;
    int v[4]; int s = 0;
#pragma unroll
    for (int i = 0; i < 4; ++i) {
        int idx = base + t * 4 + i;
        v[i] = (idx < n) ? deg[idx] : 0;
        s += v[i];
    }
    sd[t] = s;
    __syncthreads();
    for (int off = 1; off < 256; off <<= 1) {
        int x = (t >= off) ? sd[t - off] : 0;
        __syncthreads();
        sd[t] += x;
        __syncthreads();
    }
    if (t == 255) bsum[blockIdx.x] = sd[255];
    int run = sd[t] - s;
#pragma unroll
    for (int i = 0; i < 4; ++i) {
        int idx = base + t * 4 + i;
        if (idx < n) offs[idx] = run;
        run += v[i];
    }
}

// ---------------- scan stage 2: scan the block sums (nb <= 128) --------------
__global__ void k_scan2(int* __restrict__ bsum, int nb, int* __restrict__ offs_total) {
    __shared__ int sd[128];
    int t = threadIdx.x;
    int v = (t < nb) ? bsum[t] : 0;
    sd[t] = v;
    __syncthreads();
    for (int off = 1; off < 128; off <<= 1) {
        int x = (t >= off) ? sd[t - off] : 0;
        __syncthreads();
        sd[t] += x;
        __syncthreads();
    }
    if (t < nb) bsum[t] = sd[t] - v;
    if (t == 127) offs_total[0] = sd[127];
}

// -------- scan stage 3: add block offsets, copy cursor, compute dinv ---------
__global__ void k_scan3(int* __restrict__ offs, const int* __restrict__ bsum,
                        int* __restrict__ cursor, const int* __restrict__ deg,
                        float* __restrict__ dinv, int n) {
    int i = blockIdx.x * blockDim.x + threadIdx.x;
    if (i < n) {
        int v = offs[i] + bsum[i >> 10];
        offs[i] = v;
        cursor[i] = v;
        dinv[i] = 1.0f / sqrtf((float)deg[i] + 1.0f);
    }
}

// ---------------- XCD-partitioned CSR fill ----------------
__global__ __launch_bounds__(256) void k_fill_part(
    const int* __restrict__ row, const int* __restrict__ col, int E,
    int chunk, float partScale,
    int* __restrict__ cursor, int* __restrict__ csr) {
    int part = blockIdx.x & 7;
    int cb = blockIdx.x >> 3;
    int s = cb * chunk;
    int e = s + chunk; if (e > E) e = E;
    for (int i = s + threadIdx.x; i < e; i += 256) {
        int c = col[i];
        int p = (int)((float)c * partScale);
        p = p > 7 ? 7 : p;
        if (p == part) {
            int slot = atomicAdd(&cursor[c], 1);
            csr[slot] = row[i];
        }
    }
}

// ---------------- matmul [N,128]@[128,128] -> bf16 table, scaled by dinv -----
// Block: 256 threads, 32 rows x 128 cols; thread = 4 rows x 4 cols.
__global__ __launch_bounds__(256) void k_matmul_scale(
    const float* __restrict__ A, const float* __restrict__ W,
    const float* __restrict__ dinv, ushort_t* __restrict__ Cb, int N) {
    __shared__ float As[32 * 132];   // 16.9 KB
    __shared__ float Ws[64 * 128];   // 32 KB
    int t = threadIdx.x;
    int row0 = blockIdx.x * 32;
    int rows = N - row0; if (rows > 32) rows = 32;

    {   // stage A tile
        const float4* Ag = (const float4*)(A + (size_t)row0 * C_DIM);
        for (int i = t; i < rows * 32; i += 256) {
            int r = i >> 5, kq = i & 31;
            float4 v = Ag[i];
            *(float4*)&As[r * 132 + kq * 4] = v;
        }
    }

    int cg = (t & 31) * 4;       // col base 0..124
    int rg = (t >> 5) * 4;       // row base 0..28
    float acc[4][4] = {};

    for (int kh = 0; kh < 2; ++kh) {
        __syncthreads();
        {
            const float4* Wg = (const float4*)(W + (size_t)kh * 64 * C_DIM);
            float4* Wsv = (float4*)Ws;
            for (int i = t; i < 64 * 32; i += 256) Wsv[i] = Wg[i];
        }
        __syncthreads();
        for (int k = 0; k < 64; k += 4) {
            float4 a[4];
#pragma unroll
            for (int i = 0; i < 4; ++i)
                a[i] = *(const float4*)&As[(rg + i) * 132 + kh * 64 + k];
#pragma unroll
            for (int kk = 0; kk < 4; ++kk) {
                float4 w = *(const float4*)&Ws[(k + kk) * C_DIM + cg];
#pragma unroll
                for (int i = 0; i < 4; ++i) {
                    float av = (kk == 0) ? a[i].x : (kk == 1) ? a[i].y
                             : (kk == 2) ? a[i].z : a[i].w;
                    acc[i][0] += av * w.x;
                    acc[i][1] += av * w.y;
                    acc[i][2] += av * w.z;
                    acc[i][3] += av * w.w;
                }
            }
        }
    }

#pragma unroll
    for (int i = 0; i < 4; ++i) {
        if (rg + i < rows) {
            int r = row0 + rg + i;
            float s = dinv[r];
            ushort4 o;
            o.x = f2bf(acc[i][0] * s); o.y = f2bf(acc[i][1] * s);
            o.z = f2bf(acc[i][2] * s); o.w = f2bf(acc[i][3] * s);
            *(ushort4*)&Cb[(size_t)r * C_DIM + cg] = o;
        }
    }
}

// ---------------- per-node gather-reduce aggregation (bf16 table) ------------
// 4 waves/block, one node per wave. Lane t holds features 2t,2t+1 (one dword).
// out = act(dinv[n]*(sum+self)+b) in fp32.
__global__ __launch_bounds__(256) void k_aggregate(
    const ushort_t* __restrict__ hs, const int* __restrict__ offs,
    const int* __restrict__ csr, const float* __restrict__ dinv,
    const float* __restrict__ bias, float* __restrict__ out, int do_relu, int N) {
    int node = (blockIdx.x << 2) + (threadIdx.x >> 6);
    if (node >= N) return;
    int t = threadIdx.x & 63;
    int s = offs[node], e = offs[node + 1];
    float ax, ay;
    {   // self-loop
        unsigned u = ((const unsigned*)(hs + (size_t)node * C_DIM))[t];
        ax = bf2f(u & 0xFFFFu); ay = bf2f(u >> 16);
    }
    int j = s;
    for (; j + 8 <= e; j += 8) {
        int r[8];
#pragma unroll
        for (int k = 0; k < 8; ++k) r[k] = csr[j + k];
        unsigned u[8];
#pragma unroll
        for (int k = 0; k < 8; ++k)
            u[k] = ((const unsigned*)(hs + (size_t)r[k] * C_DIM))[t];
#pragma unroll
        for (int k = 0; k < 8; ++k) {
            ax += bf2f(u[k] & 0xFFFFu);
            ay += bf2f(u[k] >> 16);
        }
    }
    for (; j + 2 <= e; j += 2) {
        int r0 = csr[j], r1 = csr[j + 1];
        unsigned u0 = ((const unsigned*)(hs + (size_t)r0 * C_DIM))[t];
        unsigned u1 = ((const unsigned*)(hs + (size_t)r1 * C_DIM))[t];
        ax += bf2f(u0 & 0xFFFFu) + bf2f(u1 & 0xFFFFu);
        ay += bf2f(u0 >> 16) + bf2f(u1 >> 16);
    }
    if (j < e) {
        unsigned u = ((const unsigned*)(hs + (size_t)csr[j] * C_DIM))[t];
        ax += bf2f(u & 0xFFFFu); ay += bf2f(u >> 16);
    }
    float dn = dinv[node];
    float ox = dn * ax + bias[2 * t];
    float oy = dn * ay + bias[2 * t + 1];
    if (do_relu) { ox = fmaxf(ox, 0.f); oy = fmaxf(oy, 0.f); }
    ((float2*)(out + (size_t)node * C_DIM))[t] = make_float2(ox, oy);
}

// ---------------- fused scatter-mean pool + MLP (128->64->1) ----------------
__global__ __launch_bounds__(128) void k_pool_mlp(
    const float* __restrict__ h, const int* __restrict__ batch, int n,
    const float* __restrict__ Wm1, const float* __restrict__ bm1,
    const float* __restrict__ Wm2, const float* __restrict__ bm2,
    float* __restrict__ out) {
    int g = blockIdx.x;
    int t = threadIdx.x;
    int lo = 0, hi = n;
    while (lo < hi) { int m = (lo + hi) >> 1; if (batch[m] < g) lo = m + 1; else hi = m; }
    int start = lo;
    lo = start; hi = n;
    while (lo < hi) { int m = (lo + hi) >> 1; if (batch[m] < g + 1) lo = m + 1; else hi = m; }
    int end = lo;

    float s = 0.f;
    for (int i = start; i < end; ++i) s += h[(size_t)i * C_DIM + t];
    float cnt = (float)(end - start);
    float mean = s / fmaxf(cnt, 1.0f);

    __shared__ float m_s[128];
    __shared__ float hid[64];
    m_s[t] = mean;
    __syncthreads();
    if (t < 64) {
        float a = bm1[t];
#pragma unroll 4
        for (int k = 0; k < 128; ++k) a += m_s[k] * Wm1[k * 64 + t];
        hid[t] = fmaxf(a, 0.f) * Wm2[t];
    }
    __syncthreads();
    if (t < 64) {
        float v = hid[t];
        for (int off = 32; off > 0; off >>= 1) v += __shfl_down(v, off);
        if (t == 0) out[g] = v + bm2[0];
    }
}

extern "C" void kernel_launch(void* const* d_in, const int* in_sizes, int n_in,
                              void* d_out, int out_size, void* d_ws, size_t ws_size,
                              hipStream_t stream) {
    const float* x     = (const float*)d_in[0];
    const int*   eidx  = (const int*)d_in[1];
    const int*   batch = (const int*)d_in[2];
    const float* W1    = (const float*)d_in[3];
    const float* b1    = (const float*)d_in[4];
    const float* W2    = (const float*)d_in[5];
    const float* b2    = (const float*)d_in[6];
    const float* Wm1   = (const float*)d_in[7];
    const float* bm1   = (const float*)d_in[8];
    const float* Wm2   = (const float*)d_in[9];
    const float* bm2   = (const float*)d_in[10];

    const int N = in_sizes[2];       // 100000
    const int E = in_sizes[1] / 2;   // 1600000
    const int G = out_size;          // 512

    char* p = (char*)d_ws;
    auto carve = [&](size_t bytes) {
        char* q = p;
        p += (bytes + 255) & ~(size_t)255;
        return q;
    };
    float*    bufF   = (float*)   carve((size_t)N * C_DIM * sizeof(float));  // fp32 agg out
    ushort_t* bufH   = (ushort_t*)carve((size_t)N * C_DIM * sizeof(ushort_t)); // bf16 table
    float*    dinv   = (float*)   carve((size_t)N * sizeof(float));
    int*      deg    = (int*)     carve((size_t)N * sizeof(int));
    int*      offs   = (int*)     carve((size_t)(N + 1) * sizeof(int));
    int*      cursor = (int*)     carve((size_t)N * sizeof(int));
    int*      csr    = (int*)     carve((size_t)E * sizeof(int));
    int*      bsum   = (int*)     carve(128 * sizeof(int));

    const int* erow = eidx;
    const int* ecol = eidx + E;

    const float partScale = 8.0f / (float)N;
    const int nBlkPerPart = 256;
    const int chunk = ceil_div(E, nBlkPerPart);

    // --- CSR-by-destination build (once per call) ---
    hipMemsetAsync(deg, 0, (size_t)N * sizeof(int), stream);
    k_count_part<<<8 * nBlkPerPart, 256, 0, stream>>>(ecol, E, chunk, partScale, deg);
    int nb = ceil_div(N, 1024);
    k_scan1<<<nb, 256, 0, stream>>>(deg, N, offs, bsum);
    k_scan2<<<1, 128, 0, stream>>>(bsum, nb, offs + N);
    k_scan3<<<ceil_div(N, 256), 256, 0, stream>>>(offs, bsum, cursor, deg, dinv, N);
    k_fill_part<<<8 * nBlkPerPart, 256, 0, stream>>>(erow, ecol, E, chunk, partScale,
                                                     cursor, csr);

    // --- conv1: bufH = bf16(dinv ⊙ (x@W1)); bufF = relu(dinv*(agg+self)+b1) ---
    k_matmul_scale<<<ceil_div(N, 32), 256, 0, stream>>>(x, W1, dinv, bufH, N);
    k_aggregate<<<ceil_div(N, 4), 256, 0, stream>>>(bufH, offs, csr, dinv, b1, bufF, 1, N);
    // --- conv2 ---
    k_matmul_scale<<<ceil_div(N, 32), 256, 0, stream>>>(bufF, W2, dinv, bufH, N);
    k_aggregate<<<ceil_div(N, 4), 256, 0, stream>>>(bufH, offs, csr, dinv, b2, bufF, 0, N);
    // --- pool + MLP ---
    k_pool_mlp<<<G, 128, 0, stream>>>(bufF, batch, N, Wm1, bm1, Wm2, bm2, (float*)d_out);
}

// Round 4
// 518.682 us; speedup vs baseline: 1.3885x; 1.0891x over previous
//
#include <hip/hip_runtime.h>
#include <math.h>

#define C_DIM 128
#define POOL_CHUNK 64
typedef unsigned short ushort_t;

static inline int ceil_div(int a, int b) { return (a + b - 1) / b; }

// bf16 round-to-nearest-even (unbiased — truncation would bias sums by deg*2^-9)
__device__ inline ushort_t f2bf(float f) {
    union { float f; unsigned u; } v; v.f = f;
    unsigned r = v.u + 0x7FFFu + ((v.u >> 16) & 1u);
    return (ushort_t)(r >> 16);
}
__device__ inline float bf2f(unsigned s) {
    union { unsigned u; float f; } v; v.u = s << 16; return v.f;
}

// ---------------- XCD-partitioned degree count (in-degree over col) ----------
__global__ __launch_bounds__(256) void k_count_part(
    const int* __restrict__ col, int E, int chunk, float partScale,
    int* __restrict__ deg) {
    int part = blockIdx.x & 7;
    int cb = blockIdx.x >> 3;
    int s = cb * chunk;
    int e = s + chunk; if (e > E) e = E;
    for (int i = s + threadIdx.x; i < e; i += 256) {
        int c = col[i];
        int p = (int)((float)c * partScale);
        p = p > 7 ? 7 : p;
        if (p == part) atomicAdd(&deg[c], 1);
    }
}

// ---------------- scan stage 1: per-1024-block exclusive scan ----------------
__global__ void k_scan1(const int* __restrict__ deg, int n,
                        int* __restrict__ offs, int* __restrict__ bsum) {
    __shared__ int sd[256];
    int t = threadIdx.x;
    int base = blockIdx.x * 1024;
    int v[4]; int s = 0;
#pragma unroll
    for (int i = 0; i < 4; ++i) {
        int idx = base + t * 4 + i;
        v[i] = (idx < n) ? deg[idx] : 0;
        s += v[i];
    }
    sd[t] = s;
    __syncthreads();
    for (int off = 1; off < 256; off <<= 1) {
        int x = (t >= off) ? sd[t - off] : 0;
        __syncthreads();
        sd[t] += x;
        __syncthreads();
    }
    if (t == 255) bsum[blockIdx.x] = sd[255];
    int run = sd[t] - s;
#pragma unroll
    for (int i = 0; i < 4; ++i) {
        int idx = base + t * 4 + i;
        if (idx < n) offs[idx] = run;
        run += v[i];
    }
}

// ---------------- scan stage 2: scan the block sums (nb <= 128) --------------
__global__ void k_scan2(int* __restrict__ bsum, int nb, int* __restrict__ offs_total) {
    __shared__ int sd[128];
    int t = threadIdx.x;
    int v = (t < nb) ? bsum[t] : 0;
    sd[t] = v;
    __syncthreads();
    for (int off = 1; off < 128; off <<= 1) {
        int x = (t >= off) ? sd[t - off] : 0;
        __syncthreads();
        sd[t] += x;
        __syncthreads();
    }
    if (t < nb) bsum[t] = sd[t] - v;
    if (t == 127) offs_total[0] = sd[127];
}

// -------- scan stage 3: add block offsets, copy cursor, compute dinv ---------
__global__ void k_scan3(int* __restrict__ offs, const int* __restrict__ bsum,
                        int* __restrict__ cursor, const int* __restrict__ deg,
                        float* __restrict__ dinv, int n) {
    int i = blockIdx.x * blockDim.x + threadIdx.x;
    if (i < n) {
        int v = offs[i] + bsum[i >> 10];
        offs[i] = v;
        cursor[i] = v;
        dinv[i] = 1.0f / sqrtf((float)deg[i] + 1.0f);
    }
}

// ---------------- XCD-partitioned CSR fill ----------------
__global__ __launch_bounds__(256) void k_fill_part(
    const int* __restrict__ row, const int* __restrict__ col, int E,
    int chunk, float partScale,
    int* __restrict__ cursor, int* __restrict__ csr) {
    int part = blockIdx.x & 7;
    int cb = blockIdx.x >> 3;
    int s = cb * chunk;
    int e = s + chunk; if (e > E) e = E;
    for (int i = s + threadIdx.x; i < e; i += 256) {
        int c = col[i];
        int p = (int)((float)c * partScale);
        p = p > 7 ? 7 : p;
        if (p == part) {
            int slot = atomicAdd(&cursor[c], 1);
            csr[slot] = row[i];
        }
    }
}

// ---------------- matmul [N,128]@[128,128] -> bf16 table, scaled by dinv -----
__global__ __launch_bounds__(256) void k_matmul_scale(
    const float* __restrict__ A, const float* __restrict__ W,
    const float* __restrict__ dinv, ushort_t* __restrict__ Cb, int N) {
    __shared__ float As[32 * 132];   // 16.9 KB
    __shared__ float Ws[64 * 128];   // 32 KB
    int t = threadIdx.x;
    int row0 = blockIdx.x * 32;
    int rows = N - row0; if (rows > 32) rows = 32;

    {   // stage A tile
        const float4* Ag = (const float4*)(A + (size_t)row0 * C_DIM);
        for (int i = t; i < rows * 32; i += 256) {
            int r = i >> 5, kq = i & 31;
            float4 v = Ag[i];
            *(float4*)&As[r * 132 + kq * 4] = v;
        }
    }

    int cg = (t & 31) * 4;       // col base 0..124
    int rg = (t >> 5) * 4;       // row base 0..28
    float acc[4][4] = {};

    for (int kh = 0; kh < 2; ++kh) {
        __syncthreads();
        {
            const float4* Wg = (const float4*)(W + (size_t)kh * 64 * C_DIM);
            float4* Wsv = (float4*)Ws;
            for (int i = t; i < 64 * 32; i += 256) Wsv[i] = Wg[i];
        }
        __syncthreads();
        for (int k = 0; k < 64; k += 4) {
            float4 a[4];
#pragma unroll
            for (int i = 0; i < 4; ++i)
                a[i] = *(const float4*)&As[(rg + i) * 132 + kh * 64 + k];
#pragma unroll
            for (int kk = 0; kk < 4; ++kk) {
                float4 w = *(const float4*)&Ws[(k + kk) * C_DIM + cg];
#pragma unroll
                for (int i = 0; i < 4; ++i) {
                    float av = (kk == 0) ? a[i].x : (kk == 1) ? a[i].y
                             : (kk == 2) ? a[i].z : a[i].w;
                    acc[i][0] += av * w.x;
                    acc[i][1] += av * w.y;
                    acc[i][2] += av * w.z;
                    acc[i][3] += av * w.w;
                }
            }
        }
    }

#pragma unroll
    for (int i = 0; i < 4; ++i) {
        if (rg + i < rows) {
            int r = row0 + rg + i;
            float s = dinv[r];
            ushort4 o;
            o.x = f2bf(acc[i][0] * s); o.y = f2bf(acc[i][1] * s);
            o.z = f2bf(acc[i][2] * s); o.w = f2bf(acc[i][3] * s);
            *(ushort4*)&Cb[(size_t)r * C_DIM + cg] = o;
        }
    }
}

// ---------------- per-node gather-reduce aggregation (bf16 table) ------------
__global__ __launch_bounds__(256) void k_aggregate(
    const ushort_t* __restrict__ hs, const int* __restrict__ offs,
    const int* __restrict__ csr, const float* __restrict__ dinv,
    const float* __restrict__ bias, float* __restrict__ out, int do_relu, int N) {
    int node = (blockIdx.x << 2) + (threadIdx.x >> 6);
    if (node >= N) return;
    int t = threadIdx.x & 63;
    int s = offs[node], e = offs[node + 1];
    float ax, ay;
    {   // self-loop
        unsigned u = ((const unsigned*)(hs + (size_t)node * C_DIM))[t];
        ax = bf2f(u & 0xFFFFu); ay = bf2f(u >> 16);
    }
    int j = s;
    for (; j + 8 <= e; j += 8) {
        int r[8];
#pragma unroll
        for (int k = 0; k < 8; ++k) r[k] = csr[j + k];
        unsigned u[8];
#pragma unroll
        for (int k = 0; k < 8; ++k)
            u[k] = ((const unsigned*)(hs + (size_t)r[k] * C_DIM))[t];
#pragma unroll
        for (int k = 0; k < 8; ++k) {
            ax += bf2f(u[k] & 0xFFFFu);
            ay += bf2f(u[k] >> 16);
        }
    }
    for (; j + 2 <= e; j += 2) {
        int r0 = csr[j], r1 = csr[j + 1];
        unsigned u0 = ((const unsigned*)(hs + (size_t)r0 * C_DIM))[t];
        unsigned u1 = ((const unsigned*)(hs + (size_t)r1 * C_DIM))[t];
        ax += bf2f(u0 & 0xFFFFu) + bf2f(u1 & 0xFFFFu);
        ay += bf2f(u0 >> 16) + bf2f(u1 >> 16);
    }
    if (j < e) {
        unsigned u = ((const unsigned*)(hs + (size_t)csr[j] * C_DIM))[t];
        ax += bf2f(u & 0xFFFFu); ay += bf2f(u >> 16);
    }
    float dn = dinv[node];
    float ox = dn * ax + bias[2 * t];
    float oy = dn * ay + bias[2 * t + 1];
    if (do_relu) { ox = fmaxf(ox, 0.f); oy = fmaxf(oy, 0.f); }
    ((float2*)(out + (size_t)node * C_DIM))[t] = make_float2(ox, oy);
}

// ---------------- pool stage 1: segmented partial sums ----------------
// Block = 64 contiguous rows x 128 threads (1 col each). batch is sorted, so a
// chunk spans ~1.3 graph segments; one atomicAdd per (segment, col).
__global__ __launch_bounds__(128) void k_pool_sum(
    const float* __restrict__ h, const int* __restrict__ batch, int n,
    float* __restrict__ sums) {
    int r0 = blockIdx.x * POOL_CHUNK;
    int r1 = r0 + POOL_CHUNK; if (r1 > n) r1 = n;
    if (r0 >= n) return;
    int t = threadIdx.x;
    int g = batch[r0];
    float run = 0.f;
    int i = r0;
    while (i < r1) {
        if (i + 4 <= r1 && batch[i + 3] == g) {   // fast path: uniform branch
            float a0 = h[(size_t)i * C_DIM + t];
            float a1 = h[(size_t)(i + 1) * C_DIM + t];
            float a2 = h[(size_t)(i + 2) * C_DIM + t];
            float a3 = h[(size_t)(i + 3) * C_DIM + t];
            run += (a0 + a1) + (a2 + a3);
            i += 4;
        } else {
            int bi = batch[i];
            if (bi != g) { atomicAdd(&sums[(size_t)g * C_DIM + t], run); run = 0.f; g = bi; }
            run += h[(size_t)i * C_DIM + t];
            ++i;
        }
    }
    atomicAdd(&sums[(size_t)g * C_DIM + t], run);
}

// ---------------- pool stage 2: mean + MLP (128->64->1) ----------------
__global__ __launch_bounds__(128) void k_mlp(
    const float* __restrict__ sums, const int* __restrict__ batch, int n,
    const float* __restrict__ Wm1, const float* __restrict__ bm1,
    const float* __restrict__ Wm2, const float* __restrict__ bm2,
    float* __restrict__ out) {
    int g = blockIdx.x;
    int t = threadIdx.x;
    // per-graph node count via binary searches on sorted batch
    int lo = 0, hi = n;
    while (lo < hi) { int m = (lo + hi) >> 1; if (batch[m] < g) lo = m + 1; else hi = m; }
    int start = lo;
    lo = start; hi = n;
    while (lo < hi) { int m = (lo + hi) >> 1; if (batch[m] < g + 1) lo = m + 1; else hi = m; }
    float cnt = (float)(lo - start);

    float mean = sums[(size_t)g * C_DIM + t] / fmaxf(cnt, 1.0f);

    __shared__ float m_s[128];
    __shared__ float hid[64];
    m_s[t] = mean;
    __syncthreads();
    if (t < 64) {
        float a = bm1[t];
#pragma unroll 4
        for (int k = 0; k < 128; ++k) a += m_s[k] * Wm1[k * 64 + t];
        hid[t] = fmaxf(a, 0.f) * Wm2[t];
    }
    __syncthreads();
    if (t < 64) {
        float v = hid[t];
        for (int off = 32; off > 0; off >>= 1) v += __shfl_down(v, off);
        if (t == 0) out[g] = v + bm2[0];
    }
}

extern "C" void kernel_launch(void* const* d_in, const int* in_sizes, int n_in,
                              void* d_out, int out_size, void* d_ws, size_t ws_size,
                              hipStream_t stream) {
    const float* x     = (const float*)d_in[0];
    const int*   eidx  = (const int*)d_in[1];
    const int*   batch = (const int*)d_in[2];
    const float* W1    = (const float*)d_in[3];
    const float* b1    = (const float*)d_in[4];
    const float* W2    = (const float*)d_in[5];
    const float* b2    = (const float*)d_in[6];
    const float* Wm1   = (const float*)d_in[7];
    const float* bm1   = (const float*)d_in[8];
    const float* Wm2   = (const float*)d_in[9];
    const float* bm2   = (const float*)d_in[10];

    const int N = in_sizes[2];       // 100000
    const int E = in_sizes[1] / 2;   // 1600000
    const int G = out_size;          // 512

    char* p = (char*)d_ws;
    auto carve = [&](size_t bytes) {
        char* q = p;
        p += (bytes + 255) & ~(size_t)255;
        return q;
    };
    float*    bufF   = (float*)   carve((size_t)N * C_DIM * sizeof(float));
    ushort_t* bufH   = (ushort_t*)carve((size_t)N * C_DIM * sizeof(ushort_t));
    float*    dinv   = (float*)   carve((size_t)N * sizeof(float));
    int*      deg    = (int*)     carve((size_t)N * sizeof(int));
    int*      offs   = (int*)     carve((size_t)(N + 1) * sizeof(int));
    int*      cursor = (int*)     carve((size_t)N * sizeof(int));
    int*      csr    = (int*)     carve((size_t)E * sizeof(int));
    int*      bsum   = (int*)     carve(128 * sizeof(int));
    float*    gsums  = (float*)   carve((size_t)G * C_DIM * sizeof(float));

    const int* erow = eidx;
    const int* ecol = eidx + E;

    const float partScale = 8.0f / (float)N;
    const int nBlkPerPart = 256;
    const int chunk = ceil_div(E, nBlkPerPart);

    // --- CSR-by-destination build (once per call) ---
    hipMemsetAsync(deg, 0, (size_t)N * sizeof(int), stream);
    hipMemsetAsync(gsums, 0, (size_t)G * C_DIM * sizeof(float), stream);
    k_count_part<<<8 * nBlkPerPart, 256, 0, stream>>>(ecol, E, chunk, partScale, deg);
    int nb = ceil_div(N, 1024);
    k_scan1<<<nb, 256, 0, stream>>>(deg, N, offs, bsum);
    k_scan2<<<1, 128, 0, stream>>>(bsum, nb, offs + N);
    k_scan3<<<ceil_div(N, 256), 256, 0, stream>>>(offs, bsum, cursor, deg, dinv, N);
    k_fill_part<<<8 * nBlkPerPart, 256, 0, stream>>>(erow, ecol, E, chunk, partScale,
                                                     cursor, csr);

    // --- conv1: bufH = bf16(dinv ⊙ (x@W1)); bufF = relu(dinv*(agg+self)+b1) ---
    k_matmul_scale<<<ceil_div(N, 32), 256, 0, stream>>>(x, W1, dinv, bufH, N);
    k_aggregate<<<ceil_div(N, 4), 256, 0, stream>>>(bufH, offs, csr, dinv, b1, bufF, 1, N);
    // --- conv2 ---
    k_matmul_scale<<<ceil_div(N, 32), 256, 0, stream>>>(bufF, W2, dinv, bufH, N);
    k_aggregate<<<ceil_div(N, 4), 256, 0, stream>>>(bufH, offs, csr, dinv, b2, bufF, 0, N);
    // --- pool (2-stage) + MLP ---
    k_pool_sum<<<ceil_div(N, POOL_CHUNK), 128, 0, stream>>>(bufF, batch, N, gsums);
    k_mlp<<<G, 128, 0, stream>>>(gsums, batch, N, Wm1, bm1, Wm2, bm2, (float*)d_out);
}

// Round 5
// 416.187 us; speedup vs baseline: 1.7304x; 1.2463x over previous
//
#include <hip/hip_runtime.h>
#include <math.h>

#define C_DIM 128
#define POOL_CHUNK 64
#define BKT_SHIFT 7          // 128 nodes per destination bucket
#define MAX_B 1024           // LDS histogram capacity (B = ceil(N/128) = 782)
#define CB 256               // edge chunk blocks
typedef unsigned short ushort_t;

static inline int ceil_div(int a, int b) { return (a + b - 1) / b; }

// bf16 round-to-nearest-even (unbiased — truncation would bias sums by deg*2^-9)
__device__ inline ushort_t f2bf(float f) {
    union { float f; unsigned u; } v; v.f = f;
    unsigned r = v.u + 0x7FFFu + ((v.u >> 16) & 1u);
    return (ushort_t)(r >> 16);
}
__device__ inline float bf2f(unsigned s) {
    union { unsigned u; float f; } v; v.u = s << 16; return v.f;
}

// ============ CSR build: two-level bucket sort, LDS atomics only ============

// Pass A: per-chunk-block LDS histogram over destination buckets.
__global__ __launch_bounds__(256) void k_bcount(
    const int* __restrict__ col, int E, int chunk, int B,
    int* __restrict__ counts) {
    __shared__ int hist[MAX_B];
    int t = threadIdx.x;
    for (int i = t; i < B; i += 256) hist[i] = 0;
    __syncthreads();
    int s = blockIdx.x * chunk;
    int e = s + chunk; if (e > E) e = E;
    for (int i = s + t; i < e; i += 256)
        atomicAdd(&hist[col[i] >> BKT_SHIFT], 1);
    __syncthreads();
    for (int i = t; i < B; i += 256)
        counts[(size_t)i * CB + blockIdx.x] = hist[i];
}

// Pass B: per-bucket exclusive scan over the CB block counts.
__global__ __launch_bounds__(256) void k_bscan(
    int* __restrict__ counts, int* __restrict__ btot) {
    __shared__ int sd[256];
    int b = blockIdx.x, t = threadIdx.x;
    int v = counts[(size_t)b * CB + t];
    sd[t] = v;
    __syncthreads();
    for (int off = 1; off < 256; off <<= 1) {
        int x = (t >= off) ? sd[t - off] : 0;
        __syncthreads();
        sd[t] += x;
        __syncthreads();
    }
    counts[(size_t)b * CB + t] = sd[t] - v;   // exclusive within bucket
    if (t == 255) btot[b] = sd[255];
}

// Pass B2: scan bucket totals -> bucket edge-region bases; also offs[N]=E.
__global__ __launch_bounds__(256) void k_btotscan(
    const int* __restrict__ btot, int* __restrict__ bbase, int B, int E,
    int* __restrict__ offs, int N) {
    __shared__ int sd[256];
    __shared__ int carry_s;
    int t = threadIdx.x;
    if (t == 0) carry_s = 0;
    __syncthreads();
    int nc = (B + 255) / 256;
    for (int c = 0; c < nc; ++c) {
        int idx = c * 256 + t;
        int v = (idx < B) ? btot[idx] : 0;
        sd[t] = v;
        __syncthreads();
        for (int off = 1; off < 256; off <<= 1) {
            int x = (t >= off) ? sd[t - off] : 0;
            __syncthreads();
            sd[t] += x;
            __syncthreads();
        }
        int pre = sd[t] - v + carry_s;
        if (idx < B) bbase[idx] = pre;
        __syncthreads();
        if (t == 0) carry_s += sd[255];
        __syncthreads();
    }
    if (t == 0) { bbase[B] = E; offs[N] = E; }
}

// Pass C: scatter edges to bucket-sorted order. Each block's slots within a
// bucket are CONTIGUOUS (reserved by the scan) -> dense, L2-coalescable stores.
__global__ __launch_bounds__(256) void k_bscatter(
    const int* __restrict__ row, const int* __restrict__ col, int E, int chunk,
    int B, const int* __restrict__ counts, const int* __restrict__ bbase,
    int2* __restrict__ epk) {
    __shared__ int cur[MAX_B];
    int t = threadIdx.x, blk = blockIdx.x;
    for (int i = t; i < B; i += 256)
        cur[i] = bbase[i] + counts[(size_t)i * CB + blk];
    __syncthreads();
    int s = blk * chunk;
    int e = s + chunk; if (e > E) e = E;
    for (int i = s + t; i < e; i += 256) {
        int c = col[i];
        int r = row[i];
        int slot = atomicAdd(&cur[c >> BKT_SHIFT], 1);
        epk[slot] = make_int2(r, c);
    }
}

// Pass D: one block per bucket (<=128 nodes). LDS count -> LDS scan -> offs,
// dinv, and final CSR scatter (dense within the bucket's csr region).
__global__ __launch_bounds__(256) void k_bfinal(
    const int2* __restrict__ epk, const int* __restrict__ bbase, int N,
    int* __restrict__ offs, float* __restrict__ dinv, int* __restrict__ csr) {
    __shared__ int cnt[128];
    __shared__ int pre[128];
    __shared__ int cur[128];
    int bkt = blockIdx.x, t = threadIdx.x;
    int s = bbase[bkt], e = bbase[bkt + 1];
    int base = bkt << BKT_SHIFT;
    int nn = N - base; if (nn > 128) nn = 128;
    if (t < 128) cnt[t] = 0;
    __syncthreads();
    for (int i = s + t; i < e; i += 256)
        atomicAdd(&cnt[epk[i].y & 127], 1);
    __syncthreads();
    if (t < 128) pre[t] = cnt[t];
    __syncthreads();
    for (int off = 1; off < 128; off <<= 1) {
        int x = (t >= off && t < 128) ? pre[t - off] : 0;
        __syncthreads();
        if (t < 128) pre[t] += x;
        __syncthreads();
    }
    if (t < 128) {
        int ex = pre[t] - cnt[t];          // exclusive scan
        cur[t] = ex;
        if (t < nn) {
            offs[base + t] = s + ex;
            dinv[base + t] = 1.0f / sqrtf((float)cnt[t] + 1.0f);
        }
    }
    __syncthreads();
    for (int i = s + t; i < e; i += 256) {
        int2 rc = epk[i];
        int slot = atomicAdd(&cur[rc.y & 127], 1);
        csr[s + slot] = rc.x;
    }
}

// ---------------- matmul [N,128]@[128,128] -> bf16 table, scaled by dinv -----
__global__ __launch_bounds__(256) void k_matmul_scale(
    const float* __restrict__ A, const float* __restrict__ W,
    const float* __restrict__ dinv, ushort_t* __restrict__ Cb, int N) {
    __shared__ float As[32 * 132];   // 16.9 KB
    __shared__ float Ws[64 * 128];   // 32 KB
    int t = threadIdx.x;
    int row0 = blockIdx.x * 32;
    int rows = N - row0; if (rows > 32) rows = 32;

    {   // stage A tile
        const float4* Ag = (const float4*)(A + (size_t)row0 * C_DIM);
        for (int i = t; i < rows * 32; i += 256) {
            int r = i >> 5, kq = i & 31;
            float4 v = Ag[i];
            *(float4*)&As[r * 132 + kq * 4] = v;
        }
    }

    int cg = (t & 31) * 4;       // col base 0..124
    int rg = (t >> 5) * 4;       // row base 0..28
    float acc[4][4] = {};

    for (int kh = 0; kh < 2; ++kh) {
        __syncthreads();
        {
            const float4* Wg = (const float4*)(W + (size_t)kh * 64 * C_DIM);
            float4* Wsv = (float4*)Ws;
            for (int i = t; i < 64 * 32; i += 256) Wsv[i] = Wg[i];
        }
        __syncthreads();
        for (int k = 0; k < 64; k += 4) {
            float4 a[4];
#pragma unroll
            for (int i = 0; i < 4; ++i)
                a[i] = *(const float4*)&As[(rg + i) * 132 + kh * 64 + k];
#pragma unroll
            for (int kk = 0; kk < 4; ++kk) {
                float4 w = *(const float4*)&Ws[(k + kk) * C_DIM + cg];
#pragma unroll
                for (int i = 0; i < 4; ++i) {
                    float av = (kk == 0) ? a[i].x : (kk == 1) ? a[i].y
                             : (kk == 2) ? a[i].z : a[i].w;
                    acc[i][0] += av * w.x;
                    acc[i][1] += av * w.y;
                    acc[i][2] += av * w.z;
                    acc[i][3] += av * w.w;
                }
            }
        }
    }

#pragma unroll
    for (int i = 0; i < 4; ++i) {
        if (rg + i < rows) {
            int r = row0 + rg + i;
            float s = dinv[r];
            ushort4 o;
            o.x = f2bf(acc[i][0] * s); o.y = f2bf(acc[i][1] * s);
            o.z = f2bf(acc[i][2] * s); o.w = f2bf(acc[i][3] * s);
            *(ushort4*)&Cb[(size_t)r * C_DIM + cg] = o;
        }
    }
}

// ---------------- per-node gather-reduce aggregation (bf16 table) ------------
__global__ __launch_bounds__(256) void k_aggregate(
    const ushort_t* __restrict__ hs, const int* __restrict__ offs,
    const int* __restrict__ csr, const float* __restrict__ dinv,
    const float* __restrict__ bias, float* __restrict__ out, int do_relu, int N) {
    int node = (blockIdx.x << 2) + (threadIdx.x >> 6);
    if (node >= N) return;
    int t = threadIdx.x & 63;
    int s = offs[node], e = offs[node + 1];
    float ax, ay;
    {   // self-loop
        unsigned u = ((const unsigned*)(hs + (size_t)node * C_DIM))[t];
        ax = bf2f(u & 0xFFFFu); ay = bf2f(u >> 16);
    }
    int j = s;
    for (; j + 8 <= e; j += 8) {
        int r[8];
#pragma unroll
        for (int k = 0; k < 8; ++k) r[k] = csr[j + k];
        unsigned u[8];
#pragma unroll
        for (int k = 0; k < 8; ++k)
            u[k] = ((const unsigned*)(hs + (size_t)r[k] * C_DIM))[t];
#pragma unroll
        for (int k = 0; k < 8; ++k) {
            ax += bf2f(u[k] & 0xFFFFu);
            ay += bf2f(u[k] >> 16);
        }
    }
    for (; j + 2 <= e; j += 2) {
        int r0 = csr[j], r1 = csr[j + 1];
        unsigned u0 = ((const unsigned*)(hs + (size_t)r0 * C_DIM))[t];
        unsigned u1 = ((const unsigned*)(hs + (size_t)r1 * C_DIM))[t];
        ax += bf2f(u0 & 0xFFFFu) + bf2f(u1 & 0xFFFFu);
        ay += bf2f(u0 >> 16) + bf2f(u1 >> 16);
    }
    if (j < e) {
        unsigned u = ((const unsigned*)(hs + (size_t)csr[j] * C_DIM))[t];
        ax += bf2f(u & 0xFFFFu); ay += bf2f(u >> 16);
    }
    float dn = dinv[node];
    float ox = dn * ax + bias[2 * t];
    float oy = dn * ay + bias[2 * t + 1];
    if (do_relu) { ox = fmaxf(ox, 0.f); oy = fmaxf(oy, 0.f); }
    ((float2*)(out + (size_t)node * C_DIM))[t] = make_float2(ox, oy);
}

// ---------------- pool stage 1: segmented partial sums ----------------
__global__ __launch_bounds__(128) void k_pool_sum(
    const float* __restrict__ h, const int* __restrict__ batch, int n,
    float* __restrict__ sums) {
    int r0 = blockIdx.x * POOL_CHUNK;
    int r1 = r0 + POOL_CHUNK; if (r1 > n) r1 = n;
    if (r0 >= n) return;
    int t = threadIdx.x;
    int g = batch[r0];
    float run = 0.f;
    int i = r0;
    while (i < r1) {
        if (i + 4 <= r1 && batch[i + 3] == g) {
            float a0 = h[(size_t)i * C_DIM + t];
            float a1 = h[(size_t)(i + 1) * C_DIM + t];
            float a2 = h[(size_t)(i + 2) * C_DIM + t];
            float a3 = h[(size_t)(i + 3) * C_DIM + t];
            run += (a0 + a1) + (a2 + a3);
            i += 4;
        } else {
            int bi = batch[i];
            if (bi != g) { atomicAdd(&sums[(size_t)g * C_DIM + t], run); run = 0.f; g = bi; }
            run += h[(size_t)i * C_DIM + t];
            ++i;
        }
    }
    atomicAdd(&sums[(size_t)g * C_DIM + t], run);
}

// ---------------- pool stage 2: mean + MLP (128->64->1) ----------------
__global__ __launch_bounds__(128) void k_mlp(
    const float* __restrict__ sums, const int* __restrict__ batch, int n,
    const float* __restrict__ Wm1, const float* __restrict__ bm1,
    const float* __restrict__ Wm2, const float* __restrict__ bm2,
    float* __restrict__ out) {
    int g = blockIdx.x;
    int t = threadIdx.x;
    int lo = 0, hi = n;
    while (lo < hi) { int m = (lo + hi) >> 1; if (batch[m] < g) lo = m + 1; else hi = m; }
    int start = lo;
    lo = start; hi = n;
    while (lo < hi) { int m = (lo + hi) >> 1; if (batch[m] < g + 1) lo = m + 1; else hi = m; }
    float cnt = (float)(lo - start);

    float mean = sums[(size_t)g * C_DIM + t] / fmaxf(cnt, 1.0f);

    __shared__ float m_s[128];
    __shared__ float hid[64];
    m_s[t] = mean;
    __syncthreads();
    if (t < 64) {
        float a = bm1[t];
#pragma unroll 4
        for (int k = 0; k < 128; ++k) a += m_s[k] * Wm1[k * 64 + t];
        hid[t] = fmaxf(a, 0.f) * Wm2[t];
    }
    __syncthreads();
    if (t < 64) {
        float v = hid[t];
        for (int off = 32; off > 0; off >>= 1) v += __shfl_down(v, off);
        if (t == 0) out[g] = v + bm2[0];
    }
}

extern "C" void kernel_launch(void* const* d_in, const int* in_sizes, int n_in,
                              void* d_out, int out_size, void* d_ws, size_t ws_size,
                              hipStream_t stream) {
    const float* x     = (const float*)d_in[0];
    const int*   eidx  = (const int*)d_in[1];
    const int*   batch = (const int*)d_in[2];
    const float* W1    = (const float*)d_in[3];
    const float* b1    = (const float*)d_in[4];
    const float* W2    = (const float*)d_in[5];
    const float* b2    = (const float*)d_in[6];
    const float* Wm1   = (const float*)d_in[7];
    const float* bm1   = (const float*)d_in[8];
    const float* Wm2   = (const float*)d_in[9];
    const float* bm2   = (const float*)d_in[10];

    const int N = in_sizes[2];       // 100000
    const int E = in_sizes[1] / 2;   // 1600000
    const int G = out_size;          // 512
    const int B = (N + 127) >> BKT_SHIFT;   // 782 buckets

    char* p = (char*)d_ws;
    auto carve = [&](size_t bytes) {
        char* q = p;
        p += (bytes + 255) & ~(size_t)255;
        return q;
    };
    float*    bufF   = (float*)   carve((size_t)N * C_DIM * sizeof(float));
    ushort_t* bufH   = (ushort_t*)carve((size_t)N * C_DIM * sizeof(ushort_t));
    float*    dinv   = (float*)   carve((size_t)N * sizeof(float));
    int*      offs   = (int*)     carve((size_t)(N + 1) * sizeof(int));
    int*      csr    = (int*)     carve((size_t)E * sizeof(int));
    int*      counts = (int*)     carve((size_t)B * CB * sizeof(int));
    int*      btot   = (int*)     carve((size_t)B * sizeof(int));
    int*      bbase  = (int*)     carve((size_t)(B + 1) * sizeof(int));
    float*    gsums  = (float*)   carve((size_t)G * C_DIM * sizeof(float));
    // epk (bucket-sorted (row,col) pairs, 12.8 MB) aliases bufF: bufF is first
    // written by conv1's aggregate, which runs after the build is done.
    int2*     epk    = (int2*)bufF;

    const int* erow = eidx;
    const int* ecol = eidx + E;
    const int chunk = ceil_div(E, CB);

    hipMemsetAsync(gsums, 0, (size_t)G * C_DIM * sizeof(float), stream);

    // --- CSR-by-destination build: LDS atomics only, no global atomics ---
    k_bcount<<<CB, 256, 0, stream>>>(ecol, E, chunk, B, counts);
    k_bscan<<<B, 256, 0, stream>>>(counts, btot);
    k_btotscan<<<1, 256, 0, stream>>>(btot, bbase, B, E, offs, N);
    k_bscatter<<<CB, 256, 0, stream>>>(erow, ecol, E, chunk, B, counts, bbase, epk);
    k_bfinal<<<B, 256, 0, stream>>>(epk, bbase, N, offs, dinv, csr);

    // --- conv1: bufH = bf16(dinv ⊙ (x@W1)); bufF = relu(dinv*(agg+self)+b1) ---
    k_matmul_scale<<<ceil_div(N, 32), 256, 0, stream>>>(x, W1, dinv, bufH, N);
    k_aggregate<<<ceil_div(N, 4), 256, 0, stream>>>(bufH, offs, csr, dinv, b1, bufF, 1, N);
    // --- conv2 ---
    k_matmul_scale<<<ceil_div(N, 32), 256, 0, stream>>>(bufF, W2, dinv, bufH, N);
    k_aggregate<<<ceil_div(N, 4), 256, 0, stream>>>(bufH, offs, csr, dinv, b2, bufF, 0, N);
    // --- pool (2-stage) + MLP ---
    k_pool_sum<<<ceil_div(N, POOL_CHUNK), 128, 0, stream>>>(bufF, batch, N, gsums);
    k_mlp<<<G, 128, 0, stream>>>(gsums, batch, N, Wm1, bm1, Wm2, bm2, (float*)d_out);
}

// Round 6
// 346.440 us; speedup vs baseline: 2.0788x; 1.2013x over previous
//
#include <hip/hip_runtime.h>
#include <math.h>

#define C_DIM 128
#define POOL_CHUNK 64
#define BKT_SHIFT 7          // 128 nodes per destination bucket
#define MAX_B 1024           // LDS histogram capacity (B = ceil(N/128) = 782)
#define CB 256               // edge chunk blocks
typedef unsigned short ushort_t;
typedef __attribute__((ext_vector_type(8))) short short8;
typedef __attribute__((ext_vector_type(4))) float f32x4;

static inline int ceil_div(int a, int b) { return (a + b - 1) / b; }

// bf16 round-to-nearest-even (unbiased — truncation would bias sums)
__device__ inline ushort_t f2bf(float f) {
    union { float f; unsigned u; } v; v.f = f;
    unsigned r = v.u + 0x7FFFu + ((v.u >> 16) & 1u);
    return (ushort_t)(r >> 16);
}
__device__ inline float bf2f(unsigned s) {
    union { unsigned u; float f; } v; v.u = s << 16; return v.f;
}

// ============ CSR build: two-level bucket sort, LDS atomics only ============

__global__ __launch_bounds__(256) void k_bcount(
    const int* __restrict__ col, int E, int chunk, int B,
    int* __restrict__ counts) {
    __shared__ int hist[MAX_B];
    int t = threadIdx.x;
    for (int i = t; i < B; i += 256) hist[i] = 0;
    __syncthreads();
    int s = blockIdx.x * chunk;
    int e = s + chunk; if (e > E) e = E;
    for (int i = s + t; i < e; i += 256)
        atomicAdd(&hist[col[i] >> BKT_SHIFT], 1);
    __syncthreads();
    for (int i = t; i < B; i += 256)
        counts[(size_t)i * CB + blockIdx.x] = hist[i];
}

__global__ __launch_bounds__(256) void k_bscan(
    int* __restrict__ counts, int* __restrict__ btot) {
    __shared__ int sd[256];
    int b = blockIdx.x, t = threadIdx.x;
    int v = counts[(size_t)b * CB + t];
    sd[t] = v;
    __syncthreads();
    for (int off = 1; off < 256; off <<= 1) {
        int x = (t >= off) ? sd[t - off] : 0;
        __syncthreads();
        sd[t] += x;
        __syncthreads();
    }
    counts[(size_t)b * CB + t] = sd[t] - v;   // exclusive within bucket
    if (t == 255) btot[b] = sd[255];
}

__global__ __launch_bounds__(256) void k_btotscan(
    const int* __restrict__ btot, int* __restrict__ bbase, int B, int E,
    int* __restrict__ offs, int N) {
    __shared__ int sd[256];
    __shared__ int carry_s;
    int t = threadIdx.x;
    if (t == 0) carry_s = 0;
    __syncthreads();
    int nc = (B + 255) / 256;
    for (int c = 0; c < nc; ++c) {
        int idx = c * 256 + t;
        int v = (idx < B) ? btot[idx] : 0;
        sd[t] = v;
        __syncthreads();
        for (int off = 1; off < 256; off <<= 1) {
            int x = (t >= off) ? sd[t - off] : 0;
            __syncthreads();
            sd[t] += x;
            __syncthreads();
        }
        int pre = sd[t] - v + carry_s;
        if (idx < B) bbase[idx] = pre;
        __syncthreads();
        if (t == 0) carry_s += sd[255];
        __syncthreads();
    }
    if (t == 0) { bbase[B] = E; offs[N] = E; }
}

__global__ __launch_bounds__(256) void k_bscatter(
    const int* __restrict__ row, const int* __restrict__ col, int E, int chunk,
    int B, const int* __restrict__ counts, const int* __restrict__ bbase,
    int2* __restrict__ epk) {
    __shared__ int cur[MAX_B];
    int t = threadIdx.x, blk = blockIdx.x;
    for (int i = t; i < B; i += 256)
        cur[i] = bbase[i] + counts[(size_t)i * CB + blk];
    __syncthreads();
    int s = blk * chunk;
    int e = s + chunk; if (e > E) e = E;
    for (int i = s + t; i < e; i += 256) {
        int c = col[i];
        int r = row[i];
        int slot = atomicAdd(&cur[c >> BKT_SHIFT], 1);
        epk[slot] = make_int2(r, c);
    }
}

__global__ __launch_bounds__(256) void k_bfinal(
    const int2* __restrict__ epk, const int* __restrict__ bbase, int N,
    int* __restrict__ offs, float* __restrict__ dinv, int* __restrict__ csr) {
    __shared__ int cnt[128];
    __shared__ int pre[128];
    __shared__ int cur[128];
    int bkt = blockIdx.x, t = threadIdx.x;
    int s = bbase[bkt], e = bbase[bkt + 1];
    int base = bkt << BKT_SHIFT;
    int nn = N - base; if (nn > 128) nn = 128;
    if (t < 128) cnt[t] = 0;
    __syncthreads();
    for (int i = s + t; i < e; i += 256)
        atomicAdd(&cnt[epk[i].y & 127], 1);
    __syncthreads();
    if (t < 128) pre[t] = cnt[t];
    __syncthreads();
    for (int off = 1; off < 128; off <<= 1) {
        int x = (t >= off && t < 128) ? pre[t - off] : 0;
        __syncthreads();
        if (t < 128) pre[t] += x;
        __syncthreads();
    }
    if (t < 128) {
        int ex = pre[t] - cnt[t];
        cur[t] = ex;
        if (t < nn) {
            offs[base + t] = s + ex;
            dinv[base + t] = 1.0f / sqrtf((float)cnt[t] + 1.0f);
        }
    }
    __syncthreads();
    for (int i = s + t; i < e; i += 256) {
        int2 rc = epk[i];
        int slot = atomicAdd(&cur[rc.y & 127], 1);
        csr[s + slot] = rc.x;
    }
}

// ============ W -> MFMA B-fragment pre-pack (once per W, 32 KB) ============
// B-frag for 16x16x32 bf16: lane holds B[k = quad*8+j][n = lane&15], j=0..7.
// wf[(nt*4+kk)*64 + lane] = 8 bf16 packed in uint4.
__global__ __launch_bounds__(256) void k_wfrag(
    const float* __restrict__ W, uint4* __restrict__ wf) {
    int t = threadIdx.x;
    for (int f = t; f < 2048; f += 256) {
        int lane = f & 63, kkn = f >> 6;
        int kk = kkn & 3, nt = kkn >> 2;
        int n = lane & 15, quad = lane >> 4;
        union { ushort_t h[8]; uint4 v; } u;
#pragma unroll
        for (int j = 0; j < 8; ++j)
            u.h[j] = f2bf(W[(size_t)(kk * 32 + quad * 8 + j) * C_DIM + nt * 16 + n]);
        wf[f] = u.v;
    }
}

// ============ MFMA matmul [N,128]@[128,128] -> bf16 table, scaled by dinv ===
// 256 thr = 4 waves; wave computes 16 rows x 128 cols = 4 K-steps x 8 N-tiles
// of v_mfma_f32_16x16x32_bf16. A-frags straight from global (16B/lane, L1-
// reused: each row's 512B read by 16 lanes across kk). Epilogue via LDS for
// coalesced uint4 stores.
template <int ABF16>
__global__ __launch_bounds__(256) void k_matmul_mfma(
    const float* __restrict__ Af, const ushort_t* __restrict__ Abf,
    const uint4* __restrict__ wfrag, const float* __restrict__ dinv,
    ushort_t* __restrict__ Cb, int N) {
    __shared__ __align__(16) ushort_t eb[64 * 136];
    int t = threadIdx.x;
    int wv = t >> 6, lane = t & 63;
    int n = lane & 15, quad = lane >> 4;
    int row0 = blockIdx.x * 64;
    int rowA = row0 + wv * 16 + n;
    int rowAc = rowA < N ? rowA : N - 1;   // clamp (out rows never stored)

    f32x4 acc[8];
#pragma unroll
    for (int i = 0; i < 8; ++i) acc[i] = (f32x4){0.f, 0.f, 0.f, 0.f};

#pragma unroll
    for (int kk = 0; kk < 4; ++kk) {
        short8 a;
        if (ABF16) {
            uint4 u = *(const uint4*)(Abf + (size_t)rowAc * C_DIM + kk * 32 + quad * 8);
            union { uint4 v; short8 s; } c; c.v = u;
            a = c.s;
        } else {
            const float4* ap = (const float4*)(Af + (size_t)rowAc * C_DIM + kk * 32 + quad * 8);
            float4 f0 = ap[0], f1 = ap[1];
            union { ushort_t h[8]; short8 s; } c;
            c.h[0] = f2bf(f0.x); c.h[1] = f2bf(f0.y); c.h[2] = f2bf(f0.z); c.h[3] = f2bf(f0.w);
            c.h[4] = f2bf(f1.x); c.h[5] = f2bf(f1.y); c.h[6] = f2bf(f1.z); c.h[7] = f2bf(f1.w);
            a = c.s;
        }
#pragma unroll
        for (int nt = 0; nt < 8; ++nt) {
            uint4 bu = wfrag[(nt * 4 + kk) * 64 + lane];
            union { uint4 v; short8 s; } c; c.v = bu;
            acc[nt] = __builtin_amdgcn_mfma_f32_16x16x32_bf16(a, c.s, acc[nt], 0, 0, 0);
        }
    }

    // C/D layout: row = quad*4 + reg, col = nt*16 + n  (within wave's 16-rows)
#pragma unroll
    for (int reg = 0; reg < 4; ++reg) {
        int rl = wv * 16 + quad * 4 + reg;
        int r = row0 + rl;
        float s = dinv[r < N ? r : N - 1];
#pragma unroll
        for (int nt = 0; nt < 8; ++nt)
            eb[rl * 136 + nt * 16 + n] = f2bf(acc[nt][reg] * s);
    }
    __syncthreads();
    int rows = N - row0; if (rows > 64) rows = 64;
    for (int idx = t; idx < 16 * 64; idx += 256) {
        int r = idx >> 4, c8 = idx & 15;
        if (r < rows)
            *(uint4*)(Cb + (size_t)(row0 + r) * C_DIM + c8 * 8) =
                *(const uint4*)&eb[r * 136 + c8 * 8];
    }
}

// ---------------- per-node gather-reduce aggregation (bf16 in, bf16 out) -----
// 4 waves/block, one node per wave. Lane t holds features 2t,2t+1 (one dword).
// out = act(dinv[n]*(sum+self)+b), fp32 accum, bf16 RNE store.
template <int RELU>
__global__ __launch_bounds__(256) void k_aggregate(
    const ushort_t* __restrict__ hs, const int* __restrict__ offs,
    const int* __restrict__ csr, const float* __restrict__ dinv,
    const float* __restrict__ bias, unsigned* __restrict__ outU, int N) {
    int node = (blockIdx.x << 2) + (threadIdx.x >> 6);
    if (node >= N) return;
    int t = threadIdx.x & 63;
    int s = offs[node], e = offs[node + 1];
    float ax, ay;
    {   // self-loop
        unsigned u = ((const unsigned*)(hs + (size_t)node * C_DIM))[t];
        ax = bf2f(u & 0xFFFFu); ay = bf2f(u >> 16);
    }
    int j = s;
    for (; j + 8 <= e; j += 8) {
        int r[8];
#pragma unroll
        for (int k = 0; k < 8; ++k) r[k] = csr[j + k];
        unsigned u[8];
#pragma unroll
        for (int k = 0; k < 8; ++k)
            u[k] = ((const unsigned*)(hs + (size_t)r[k] * C_DIM))[t];
#pragma unroll
        for (int k = 0; k < 8; ++k) {
            ax += bf2f(u[k] & 0xFFFFu);
            ay += bf2f(u[k] >> 16);
        }
    }
    for (; j + 2 <= e; j += 2) {
        int r0 = csr[j], r1 = csr[j + 1];
        unsigned u0 = ((const unsigned*)(hs + (size_t)r0 * C_DIM))[t];
        unsigned u1 = ((const unsigned*)(hs + (size_t)r1 * C_DIM))[t];
        ax += bf2f(u0 & 0xFFFFu) + bf2f(u1 & 0xFFFFu);
        ay += bf2f(u0 >> 16) + bf2f(u1 >> 16);
    }
    if (j < e) {
        unsigned u = ((const unsigned*)(hs + (size_t)csr[j] * C_DIM))[t];
        ax += bf2f(u & 0xFFFFu); ay += bf2f(u >> 16);
    }
    float dn = dinv[node];
    float ox = dn * ax + bias[2 * t];
    float oy = dn * ay + bias[2 * t + 1];
    if (RELU) { ox = fmaxf(ox, 0.f); oy = fmaxf(oy, 0.f); }
    outU[(size_t)node * 64 + t] = (unsigned)f2bf(ox) | ((unsigned)f2bf(oy) << 16);
}

// ---------------- pool stage 1: segmented partial sums (bf16 in) -------------
__global__ __launch_bounds__(128) void k_pool_sum(
    const ushort_t* __restrict__ h, const int* __restrict__ batch, int n,
    float* __restrict__ sums) {
    int r0 = blockIdx.x * POOL_CHUNK;
    int r1 = r0 + POOL_CHUNK; if (r1 > n) r1 = n;
    if (r0 >= n) return;
    int t = threadIdx.x;
    int g = batch[r0];
    float run = 0.f;
    int i = r0;
    while (i < r1) {
        if (i + 4 <= r1 && batch[i + 3] == g) {
            float a0 = bf2f(h[(size_t)i * C_DIM + t]);
            float a1 = bf2f(h[(size_t)(i + 1) * C_DIM + t]);
            float a2 = bf2f(h[(size_t)(i + 2) * C_DIM + t]);
            float a3 = bf2f(h[(size_t)(i + 3) * C_DIM + t]);
            run += (a0 + a1) + (a2 + a3);
            i += 4;
        } else {
            int bi = batch[i];
            if (bi != g) { atomicAdd(&sums[(size_t)g * C_DIM + t], run); run = 0.f; g = bi; }
            run += bf2f(h[(size_t)i * C_DIM + t]);
            ++i;
        }
    }
    atomicAdd(&sums[(size_t)g * C_DIM + t], run);
}

// ---------------- pool stage 2: mean + MLP (128->64->1) ----------------
__global__ __launch_bounds__(128) void k_mlp(
    const float* __restrict__ sums, const int* __restrict__ batch, int n,
    const float* __restrict__ Wm1, const float* __restrict__ bm1,
    const float* __restrict__ Wm2, const float* __restrict__ bm2,
    float* __restrict__ out) {
    int g = blockIdx.x;
    int t = threadIdx.x;
    int lo = 0, hi = n;
    while (lo < hi) { int m = (lo + hi) >> 1; if (batch[m] < g) lo = m + 1; else hi = m; }
    int start = lo;
    lo = start; hi = n;
    while (lo < hi) { int m = (lo + hi) >> 1; if (batch[m] < g + 1) lo = m + 1; else hi = m; }
    float cnt = (float)(lo - start);

    float mean = sums[(size_t)g * C_DIM + t] / fmaxf(cnt, 1.0f);

    __shared__ float m_s[128];
    __shared__ float hid[64];
    m_s[t] = mean;
    __syncthreads();
    if (t < 64) {
        float a = bm1[t];
#pragma unroll 4
        for (int k = 0; k < 128; ++k) a += m_s[k] * Wm1[k * 64 + t];
        hid[t] = fmaxf(a, 0.f) * Wm2[t];
    }
    __syncthreads();
    if (t < 64) {
        float v = hid[t];
        for (int off = 32; off > 0; off >>= 1) v += __shfl_down(v, off);
        if (t == 0) out[g] = v + bm2[0];
    }
}

extern "C" void kernel_launch(void* const* d_in, const int* in_sizes, int n_in,
                              void* d_out, int out_size, void* d_ws, size_t ws_size,
                              hipStream_t stream) {
    const float* x     = (const float*)d_in[0];
    const int*   eidx  = (const int*)d_in[1];
    const int*   batch = (const int*)d_in[2];
    const float* W1    = (const float*)d_in[3];
    const float* b1    = (const float*)d_in[4];
    const float* W2    = (const float*)d_in[5];
    const float* b2    = (const float*)d_in[6];
    const float* Wm1   = (const float*)d_in[7];
    const float* bm1   = (const float*)d_in[8];
    const float* Wm2   = (const float*)d_in[9];
    const float* bm2   = (const float*)d_in[10];

    const int N = in_sizes[2];       // 100000
    const int E = in_sizes[1] / 2;   // 1600000
    const int G = out_size;          // 512
    const int B = (N + 127) >> BKT_SHIFT;   // 782 buckets

    char* p = (char*)d_ws;
    auto carve = [&](size_t bytes) {
        char* q = p;
        p += (bytes + 255) & ~(size_t)255;
        return q;
    };
    ushort_t* bufT   = (ushort_t*)carve((size_t)N * C_DIM * sizeof(ushort_t)); // matmul out (gather table)
    ushort_t* bufA   = (ushort_t*)carve((size_t)N * C_DIM * sizeof(ushort_t)); // agg out
    float*    dinv   = (float*)   carve((size_t)N * sizeof(float));
    int*      offs   = (int*)     carve((size_t)(N + 1) * sizeof(int));
    int*      csr    = (int*)     carve((size_t)E * sizeof(int));
    int*      counts = (int*)     carve((size_t)B * CB * sizeof(int));
    int*      btot   = (int*)     carve((size_t)B * sizeof(int));
    int*      bbase  = (int*)     carve((size_t)(B + 1) * sizeof(int));
    float*    gsums  = (float*)   carve((size_t)G * C_DIM * sizeof(float));
    uint4*    wf1    = (uint4*)   carve(2048 * sizeof(uint4));
    uint4*    wf2    = (uint4*)   carve(2048 * sizeof(uint4));
    // epk (bucket-sorted (row,col) pairs, 12.8 MB) aliases bufT: bufT is first
    // written by matmul1, which runs after the build is done.
    int2*     epk    = (int2*)bufT;

    const int* erow = eidx;
    const int* ecol = eidx + E;
    const int chunk = ceil_div(E, CB);

    hipMemsetAsync(gsums, 0, (size_t)G * C_DIM * sizeof(float), stream);

    // --- CSR-by-destination build: LDS atomics only, no global atomics ---
    k_bcount<<<CB, 256, 0, stream>>>(ecol, E, chunk, B, counts);
    k_bscan<<<B, 256, 0, stream>>>(counts, btot);
    k_btotscan<<<1, 256, 0, stream>>>(btot, bbase, B, E, offs, N);
    k_bscatter<<<CB, 256, 0, stream>>>(erow, ecol, E, chunk, B, counts, bbase, epk);
    k_bfinal<<<B, 256, 0, stream>>>(epk, bbase, N, offs, dinv, csr);

    // --- W fragment pre-pack ---
    k_wfrag<<<1, 256, 0, stream>>>(W1, wf1);
    k_wfrag<<<1, 256, 0, stream>>>(W2, wf2);

    // --- conv1: bufT = bf16(dinv ⊙ (x@W1)); bufA = bf16(relu(dinv*agg+b1)) ---
    k_matmul_mfma<0><<<ceil_div(N, 64), 256, 0, stream>>>(x, nullptr, wf1, dinv, bufT, N);
    k_aggregate<1><<<ceil_div(N, 4), 256, 0, stream>>>(bufT, offs, csr, dinv, b1,
                                                       (unsigned*)bufA, N);
    // --- conv2 ---
    k_matmul_mfma<1><<<ceil_div(N, 64), 256, 0, stream>>>(nullptr, bufA, wf2, dinv, bufT, N);
    k_aggregate<0><<<ceil_div(N, 4), 256, 0, stream>>>(bufT, offs, csr, dinv, b2,
                                                       (unsigned*)bufA, N);
    // --- pool (2-stage) + MLP ---
    k_pool_sum<<<ceil_div(N, POOL_CHUNK), 128, 0, stream>>>(bufA, batch, N, gsums);
    k_mlp<<<G, 128, 0, stream>>>(gsums, batch, N, Wm1, bm1, Wm2, bm2, (float*)d_out);
}

// Round 7
// 340.403 us; speedup vs baseline: 2.1156x; 1.0177x over previous
//
#include <hip/hip_runtime.h>
#include <math.h>

#define C_DIM 128
#define POOL_CHUNK 64
#define BKT_SHIFT 7          // 128 nodes per destination bucket
#define MAX_B 1024           // LDS histogram capacity (B = ceil(N/128) = 782)
#define CB 256               // edge chunk blocks
typedef unsigned short ushort_t;
typedef __attribute__((ext_vector_type(8))) short short8;
typedef __attribute__((ext_vector_type(4))) float f32x4;

static inline int ceil_div(int a, int b) { return (a + b - 1) / b; }

// bf16 round-to-nearest-even (unbiased — truncation would bias sums)
__device__ inline ushort_t f2bf(float f) {
    union { float f; unsigned u; } v; v.f = f;
    unsigned r = v.u + 0x7FFFu + ((v.u >> 16) & 1u);
    return (ushort_t)(r >> 16);
}
__device__ inline float bf2f(unsigned s) {
    union { unsigned u; float f; } v; v.u = s << 16; return v.f;
}
// low/high bf16 of a dword -> fp32 (1 VALU each: shl / and)
__device__ inline float bf_lo(unsigned u) {
    union { unsigned v; float f; } c; c.v = u << 16; return c.f;
}
__device__ inline float bf_hi(unsigned u) {
    union { unsigned v; float f; } c; c.v = u & 0xFFFF0000u; return c.f;
}
__device__ inline void accum8(uint4 u, float acc[8]) {
    acc[0] += bf_lo(u.x); acc[1] += bf_hi(u.x);
    acc[2] += bf_lo(u.y); acc[3] += bf_hi(u.y);
    acc[4] += bf_lo(u.z); acc[5] += bf_hi(u.z);
    acc[6] += bf_lo(u.w); acc[7] += bf_hi(u.w);
}

// ============ CSR build: two-level bucket sort, LDS atomics only ============

__global__ __launch_bounds__(256) void k_bcount(
    const int* __restrict__ col, int E, int chunk, int B,
    int* __restrict__ counts) {
    __shared__ int hist[MAX_B];
    int t = threadIdx.x;
    for (int i = t; i < B; i += 256) hist[i] = 0;
    __syncthreads();
    int s = blockIdx.x * chunk;              // chunk % 4 == 0, E % 4 == 0
    int e = s + chunk; if (e > E) e = E;
    for (int i = s + 4 * t; i < e; i += 1024) {
        int4 c = *(const int4*)(col + i);
        atomicAdd(&hist[c.x >> BKT_SHIFT], 1);
        atomicAdd(&hist[c.y >> BKT_SHIFT], 1);
        atomicAdd(&hist[c.z >> BKT_SHIFT], 1);
        atomicAdd(&hist[c.w >> BKT_SHIFT], 1);
    }
    __syncthreads();
    for (int i = t; i < B; i += 256)
        counts[(size_t)i * CB + blockIdx.x] = hist[i];
}

__global__ __launch_bounds__(256) void k_bscan(
    int* __restrict__ counts, int* __restrict__ btot) {
    __shared__ int sd[256];
    int b = blockIdx.x, t = threadIdx.x;
    int v = counts[(size_t)b * CB + t];
    sd[t] = v;
    __syncthreads();
    for (int off = 1; off < 256; off <<= 1) {
        int x = (t >= off) ? sd[t - off] : 0;
        __syncthreads();
        sd[t] += x;
        __syncthreads();
    }
    counts[(size_t)b * CB + t] = sd[t] - v;   // exclusive within bucket
    if (t == 255) btot[b] = sd[255];
}

__global__ __launch_bounds__(256) void k_btotscan(
    const int* __restrict__ btot, int* __restrict__ bbase, int B, int E,
    int* __restrict__ offs, int N) {
    __shared__ int sd[256];
    __shared__ int carry_s;
    int t = threadIdx.x;
    if (t == 0) carry_s = 0;
    __syncthreads();
    int nc = (B + 255) / 256;
    for (int c = 0; c < nc; ++c) {
        int idx = c * 256 + t;
        int v = (idx < B) ? btot[idx] : 0;
        sd[t] = v;
        __syncthreads();
        for (int off = 1; off < 256; off <<= 1) {
            int x = (t >= off) ? sd[t - off] : 0;
            __syncthreads();
            sd[t] += x;
            __syncthreads();
        }
        int pre = sd[t] - v + carry_s;
        if (idx < B) bbase[idx] = pre;
        __syncthreads();
        if (t == 0) carry_s += sd[255];
        __syncthreads();
    }
    if (t == 0) { bbase[B] = E; offs[N] = E; }
}

__global__ __launch_bounds__(256) void k_bscatter(
    const int* __restrict__ row, const int* __restrict__ col, int E, int chunk,
    int B, const int* __restrict__ counts, const int* __restrict__ bbase,
    int2* __restrict__ epk) {
    __shared__ int cur[MAX_B];
    int t = threadIdx.x, blk = blockIdx.x;
    for (int i = t; i < B; i += 256)
        cur[i] = bbase[i] + counts[(size_t)i * CB + blk];
    __syncthreads();
    int s = blk * chunk;
    int e = s + chunk; if (e > E) e = E;
    for (int i = s + 4 * t; i < e; i += 1024) {
        int4 c = *(const int4*)(col + i);
        int4 r = *(const int4*)(row + i);
        int s0 = atomicAdd(&cur[c.x >> BKT_SHIFT], 1); epk[s0] = make_int2(r.x, c.x);
        int s1 = atomicAdd(&cur[c.y >> BKT_SHIFT], 1); epk[s1] = make_int2(r.y, c.y);
        int s2 = atomicAdd(&cur[c.z >> BKT_SHIFT], 1); epk[s2] = make_int2(r.z, c.z);
        int s3 = atomicAdd(&cur[c.w >> BKT_SHIFT], 1); epk[s3] = make_int2(r.w, c.w);
    }
}

__global__ __launch_bounds__(256) void k_bfinal(
    const int2* __restrict__ epk, const int* __restrict__ bbase, int N,
    int* __restrict__ offs, float* __restrict__ dinv, int* __restrict__ csr) {
    __shared__ int cnt[128];
    __shared__ int pre[128];
    __shared__ int cur[128];
    int bkt = blockIdx.x, t = threadIdx.x;
    int s = bbase[bkt], e = bbase[bkt + 1];
    int base = bkt << BKT_SHIFT;
    int nn = N - base; if (nn > 128) nn = 128;
    if (t < 128) cnt[t] = 0;
    __syncthreads();
    for (int i = s + t; i < e; i += 256)
        atomicAdd(&cnt[epk[i].y & 127], 1);
    __syncthreads();
    if (t < 128) pre[t] = cnt[t];
    __syncthreads();
    for (int off = 1; off < 128; off <<= 1) {
        int x = (t >= off && t < 128) ? pre[t - off] : 0;
        __syncthreads();
        if (t < 128) pre[t] += x;
        __syncthreads();
    }
    if (t < 128) {
        int ex = pre[t] - cnt[t];
        cur[t] = ex;
        if (t < nn) {
            offs[base + t] = s + ex;
            dinv[base + t] = 1.0f / sqrtf((float)cnt[t] + 1.0f);
        }
    }
    __syncthreads();
    for (int i = s + t; i < e; i += 256) {
        int2 rc = epk[i];
        int slot = atomicAdd(&cur[rc.y & 127], 1);
        csr[s + slot] = rc.x;
    }
}

// ============ W -> MFMA B-fragment pre-pack (once per W, 32 KB) ============
__global__ __launch_bounds__(256) void k_wfrag(
    const float* __restrict__ W, uint4* __restrict__ wf) {
    int t = threadIdx.x;
    for (int f = t; f < 2048; f += 256) {
        int lane = f & 63, kkn = f >> 6;
        int kk = kkn & 3, nt = kkn >> 2;
        int n = lane & 15, quad = lane >> 4;
        union { ushort_t h[8]; uint4 v; } u;
#pragma unroll
        for (int j = 0; j < 8; ++j)
            u.h[j] = f2bf(W[(size_t)(kk * 32 + quad * 8 + j) * C_DIM + nt * 16 + n]);
        wf[f] = u.v;
    }
}

// ============ MFMA matmul [N,128]@[128,128] -> bf16 table, scaled by dinv ===
template <int ABF16>
__global__ __launch_bounds__(256) void k_matmul_mfma(
    const float* __restrict__ Af, const ushort_t* __restrict__ Abf,
    const uint4* __restrict__ wfrag, const float* __restrict__ dinv,
    ushort_t* __restrict__ Cb, int N) {
    __shared__ __align__(16) ushort_t eb[64 * 136];
    int t = threadIdx.x;
    int wv = t >> 6, lane = t & 63;
    int n = lane & 15, quad = lane >> 4;
    int row0 = blockIdx.x * 64;
    int rowA = row0 + wv * 16 + n;
    int rowAc = rowA < N ? rowA : N - 1;   // clamp (out rows never stored)

    f32x4 acc[8];
#pragma unroll
    for (int i = 0; i < 8; ++i) acc[i] = (f32x4){0.f, 0.f, 0.f, 0.f};

#pragma unroll
    for (int kk = 0; kk < 4; ++kk) {
        short8 a;
        if (ABF16) {
            uint4 u = *(const uint4*)(Abf + (size_t)rowAc * C_DIM + kk * 32 + quad * 8);
            union { uint4 v; short8 s; } c; c.v = u;
            a = c.s;
        } else {
            const float4* ap = (const float4*)(Af + (size_t)rowAc * C_DIM + kk * 32 + quad * 8);
            float4 f0 = ap[0], f1 = ap[1];
            union { ushort_t h[8]; short8 s; } c;
            c.h[0] = f2bf(f0.x); c.h[1] = f2bf(f0.y); c.h[2] = f2bf(f0.z); c.h[3] = f2bf(f0.w);
            c.h[4] = f2bf(f1.x); c.h[5] = f2bf(f1.y); c.h[6] = f2bf(f1.z); c.h[7] = f2bf(f1.w);
            a = c.s;
        }
#pragma unroll
        for (int nt = 0; nt < 8; ++nt) {
            uint4 bu = wfrag[(nt * 4 + kk) * 64 + lane];
            union { uint4 v; short8 s; } c; c.v = bu;
            acc[nt] = __builtin_amdgcn_mfma_f32_16x16x32_bf16(a, c.s, acc[nt], 0, 0, 0);
        }
    }

#pragma unroll
    for (int reg = 0; reg < 4; ++reg) {
        int rl = wv * 16 + quad * 4 + reg;
        int r = row0 + rl;
        float s = dinv[r < N ? r : N - 1];
#pragma unroll
        for (int nt = 0; nt < 8; ++nt)
            eb[rl * 136 + nt * 16 + n] = f2bf(acc[nt][reg] * s);
    }
    __syncthreads();
    int rows = N - row0; if (rows > 64) rows = 64;
    for (int idx = t; idx < 16 * 64; idx += 256) {
        int r = idx >> 4, c8 = idx & 15;
        if (r < rows)
            *(uint4*)(Cb + (size_t)(row0 + r) * C_DIM + c8 * 8) =
                *(const uint4*)&eb[r * 136 + c8 * 8];
    }
}

// ---------------- per-node gather-reduce aggregation (bf16 in/out) -----------
// One wave per node; 16 lanes cover one 256 B row (dwordx4/lane), so one load
// instruction fetches FOUR edges' rows. Lane keeps 8 fp32 accs for its
// 8-feature slice (features 8*(t&15)..+7), accumulating only its quad's
// edges; 2-step shfl_xor butterfly merges quads at the end.
template <int RELU>
__global__ __launch_bounds__(256) void k_aggregate(
    const ushort_t* __restrict__ hs, const int* __restrict__ offs,
    const int* __restrict__ csr, const float* __restrict__ dinv,
    const float* __restrict__ bias, uint4* __restrict__ outV, int N) {
    int node = (blockIdx.x << 2) + (threadIdx.x >> 6);
    if (node >= N) return;
    int t = threadIdx.x & 63;
    int q = t >> 4;         // quad 0..3: which edge of a 4-group
    int fs = t & 15;        // feature slice: features 8*fs .. 8*fs+7
    int s = offs[node], e = offs[node + 1];

    float acc[8];
    {   // self-loop: quad 0 only (others contribute 0, merged by butterfly)
        uint4 u = *(const uint4*)(hs + (size_t)node * C_DIM + fs * 8);
        float v[8];
        v[0] = bf_lo(u.x); v[1] = bf_hi(u.x);
        v[2] = bf_lo(u.y); v[3] = bf_hi(u.y);
        v[4] = bf_lo(u.z); v[5] = bf_hi(u.z);
        v[6] = bf_lo(u.w); v[7] = bf_hi(u.w);
#pragma unroll
        for (int i = 0; i < 8; ++i) acc[i] = (q == 0) ? v[i] : 0.f;
    }

    int j = s;
    for (; j + 16 <= e; j += 16) {          // 16 edges: 4 idx + 4 row loads
        int r[4];
#pragma unroll
        for (int b = 0; b < 4; ++b) r[b] = csr[j + b * 4 + q];
        uint4 u[4];
#pragma unroll
        for (int b = 0; b < 4; ++b)
            u[b] = *(const uint4*)(hs + (size_t)r[b] * C_DIM + fs * 8);
#pragma unroll
        for (int b = 0; b < 4; ++b) accum8(u[b], acc);
    }
    for (; j + 4 <= e; j += 4) {            // 4-edge groups
        int r = csr[j + q];
        uint4 u = *(const uint4*)(hs + (size_t)r * C_DIM + fs * 8);
        accum8(u, acc);
    }
    if (j + q < e) {                        // tail 1-3 edges: one per quad
        int r = csr[j + q];
        uint4 u = *(const uint4*)(hs + (size_t)r * C_DIM + fs * 8);
        accum8(u, acc);
    }

    // merge quads: lanes t, t^16, t^32, t^48 hold the same feature slice
#pragma unroll
    for (int i = 0; i < 8; ++i) {
        acc[i] += __shfl_xor(acc[i], 16);
        acc[i] += __shfl_xor(acc[i], 32);
    }

    if (q == 0) {
        float dn = dinv[node];
        float4 b0 = *(const float4*)(bias + fs * 8);
        float4 b1 = *(const float4*)(bias + fs * 8 + 4);
        float o[8];
        o[0] = dn * acc[0] + b0.x; o[1] = dn * acc[1] + b0.y;
        o[2] = dn * acc[2] + b0.z; o[3] = dn * acc[3] + b0.w;
        o[4] = dn * acc[4] + b1.x; o[5] = dn * acc[5] + b1.y;
        o[6] = dn * acc[6] + b1.z; o[7] = dn * acc[7] + b1.w;
        if (RELU) {
#pragma unroll
            for (int i = 0; i < 8; ++i) o[i] = fmaxf(o[i], 0.f);
        }
        uint4 pk;
        pk.x = (unsigned)f2bf(o[0]) | ((unsigned)f2bf(o[1]) << 16);
        pk.y = (unsigned)f2bf(o[2]) | ((unsigned)f2bf(o[3]) << 16);
        pk.z = (unsigned)f2bf(o[4]) | ((unsigned)f2bf(o[5]) << 16);
        pk.w = (unsigned)f2bf(o[6]) | ((unsigned)f2bf(o[7]) << 16);
        outV[(size_t)node * 16 + fs] = pk;   // 16 lanes x 16 B = 256 B row
    }
}

// ---------------- pool stage 1: segmented partial sums (bf16 in) -------------
__global__ __launch_bounds__(128) void k_pool_sum(
    const ushort_t* __restrict__ h, const int* __restrict__ batch, int n,
    float* __restrict__ sums) {
    int r0 = blockIdx.x * POOL_CHUNK;
    int r1 = r0 + POOL_CHUNK; if (r1 > n) r1 = n;
    if (r0 >= n) return;
    int t = threadIdx.x;
    int g = batch[r0];
    float run = 0.f;
    int i = r0;
    while (i < r1) {
        if (i + 4 <= r1 && batch[i + 3] == g) {
            float a0 = bf2f(h[(size_t)i * C_DIM + t]);
            float a1 = bf2f(h[(size_t)(i + 1) * C_DIM + t]);
            float a2 = bf2f(h[(size_t)(i + 2) * C_DIM + t]);
            float a3 = bf2f(h[(size_t)(i + 3) * C_DIM + t]);
            run += (a0 + a1) + (a2 + a3);
            i += 4;
        } else {
            int bi = batch[i];
            if (bi != g) { atomicAdd(&sums[(size_t)g * C_DIM + t], run); run = 0.f; g = bi; }
            run += bf2f(h[(size_t)i * C_DIM + t]);
            ++i;
        }
    }
    atomicAdd(&sums[(size_t)g * C_DIM + t], run);
}

// ---------------- pool stage 2: mean + MLP (128->64->1) ----------------
__global__ __launch_bounds__(128) void k_mlp(
    const float* __restrict__ sums, const int* __restrict__ batch, int n,
    const float* __restrict__ Wm1, const float* __restrict__ bm1,
    const float* __restrict__ Wm2, const float* __restrict__ bm2,
    float* __restrict__ out) {
    int g = blockIdx.x;
    int t = threadIdx.x;
    int lo = 0, hi = n;
    while (lo < hi) { int m = (lo + hi) >> 1; if (batch[m] < g) lo = m + 1; else hi = m; }
    int start = lo;
    lo = start; hi = n;
    while (lo < hi) { int m = (lo + hi) >> 1; if (batch[m] < g + 1) lo = m + 1; else hi = m; }
    float cnt = (float)(lo - start);

    float mean = sums[(size_t)g * C_DIM + t] / fmaxf(cnt, 1.0f);

    __shared__ float m_s[128];
    __shared__ float hid[64];
    m_s[t] = mean;
    __syncthreads();
    if (t < 64) {
        float a = bm1[t];
#pragma unroll 4
        for (int k = 0; k < 128; ++k) a += m_s[k] * Wm1[k * 64 + t];
        hid[t] = fmaxf(a, 0.f) * Wm2[t];
    }
    __syncthreads();
    if (t < 64) {
        float v = hid[t];
        for (int off = 32; off > 0; off >>= 1) v += __shfl_down(v, off);
        if (t == 0) out[g] = v + bm2[0];
    }
}

extern "C" void kernel_launch(void* const* d_in, const int* in_sizes, int n_in,
                              void* d_out, int out_size, void* d_ws, size_t ws_size,
                              hipStream_t stream) {
    const float* x     = (const float*)d_in[0];
    const int*   eidx  = (const int*)d_in[1];
    const int*   batch = (const int*)d_in[2];
    const float* W1    = (const float*)d_in[3];
    const float* b1    = (const float*)d_in[4];
    const float* W2    = (const float*)d_in[5];
    const float* b2    = (const float*)d_in[6];
    const float* Wm1   = (const float*)d_in[7];
    const float* bm1   = (const float*)d_in[8];
    const float* Wm2   = (const float*)d_in[9];
    const float* bm2   = (const float*)d_in[10];

    const int N = in_sizes[2];       // 100000
    const int E = in_sizes[1] / 2;   // 1600000 (E % 4 == 0)
    const int G = out_size;          // 512
    const int B = (N + 127) >> BKT_SHIFT;   // 782 buckets

    char* p = (char*)d_ws;
    auto carve = [&](size_t bytes) {
        char* q = p;
        p += (bytes + 255) & ~(size_t)255;
        return q;
    };
    ushort_t* bufT   = (ushort_t*)carve((size_t)N * C_DIM * sizeof(ushort_t)); // matmul out
    ushort_t* bufA   = (ushort_t*)carve((size_t)N * C_DIM * sizeof(ushort_t)); // agg out
    float*    dinv   = (float*)   carve((size_t)N * sizeof(float));
    int*      offs   = (int*)     carve((size_t)(N + 1) * sizeof(int));
    int*      csr    = (int*)     carve((size_t)E * sizeof(int));
    int*      counts = (int*)     carve((size_t)B * CB * sizeof(int));
    int*      btot   = (int*)     carve((size_t)B * sizeof(int));
    int*      bbase  = (int*)     carve((size_t)(B + 1) * sizeof(int));
    float*    gsums  = (float*)   carve((size_t)G * C_DIM * sizeof(float));
    uint4*    wf1    = (uint4*)   carve(2048 * sizeof(uint4));
    uint4*    wf2    = (uint4*)   carve(2048 * sizeof(uint4));
    // epk aliases bufT (dead until matmul1)
    int2*     epk    = (int2*)bufT;

    const int* erow = eidx;
    const int* ecol = eidx + E;
    const int chunk = (ceil_div(E, CB) + 3) & ~3;   // multiple of 4 for int4 loads

    hipMemsetAsync(gsums, 0, (size_t)G * C_DIM * sizeof(float), stream);

    // --- CSR-by-destination build: LDS atomics only, no global atomics ---
    k_bcount<<<CB, 256, 0, stream>>>(ecol, E, chunk, B, counts);
    k_bscan<<<B, 256, 0, stream>>>(counts, btot);
    k_btotscan<<<1, 256, 0, stream>>>(btot, bbase, B, E, offs, N);
    k_bscatter<<<CB, 256, 0, stream>>>(erow, ecol, E, chunk, B, counts, bbase, epk);
    k_bfinal<<<B, 256, 0, stream>>>(epk, bbase, N, offs, dinv, csr);

    // --- W fragment pre-pack ---
    k_wfrag<<<1, 256, 0, stream>>>(W1, wf1);
    k_wfrag<<<1, 256, 0, stream>>>(W2, wf2);

    // --- conv1 ---
    k_matmul_mfma<0><<<ceil_div(N, 64), 256, 0, stream>>>(x, nullptr, wf1, dinv, bufT, N);
    k_aggregate<1><<<ceil_div(N, 4), 256, 0, stream>>>(bufT, offs, csr, dinv, b1,
                                                       (uint4*)bufA, N);
    // --- conv2 ---
    k_matmul_mfma<1><<<ceil_div(N, 64), 256, 0, stream>>>(nullptr, bufA, wf2, dinv, bufT, N);
    k_aggregate<0><<<ceil_div(N, 4), 256, 0, stream>>>(bufT, offs, csr, dinv, b2,
                                                       (uint4*)bufA, N);
    // --- pool (2-stage) + MLP ---
    k_pool_sum<<<ceil_div(N, POOL_CHUNK), 128, 0, stream>>>(bufA, batch, N, gsums);
    k_mlp<<<G, 128, 0, stream>>>(gsums, batch, N, Wm1, bm1, Wm2, bm2, (float*)d_out);
}